// Round 4
// baseline (412.059 us; speedup 1.0000x reference)
//
#include <hip/hip_runtime.h>
#include <hip/hip_bf16.h>
#include <cmath>

typedef unsigned short u16;
typedef __attribute__((ext_vector_type(8))) short short8;
typedef __attribute__((ext_vector_type(4))) float f32x4;
typedef __attribute__((ext_vector_type(4))) unsigned short u16x4;

#define AT_B 2
#define AT_T 2048
#define AT_H 16
#define AT_D 128
#define AT_M 2048
#define NROW (AT_B*AT_T)   // 4096
#define HD   (AT_H*AT_D)   // 2048

__device__ __forceinline__ u16 f2bf(float f) {
    union { float f; unsigned u; } v; v.f = f;
    unsigned u = v.u;
    unsigned r = u + 0x7fffu + ((u >> 16) & 1u);
    return (u16)(r >> 16);
}
__device__ __forceinline__ float bf2f(u16 h) {
    union { unsigned u; float f; } v; v.u = ((unsigned)h) << 16;
    return v.f;
}
__device__ __forceinline__ unsigned pack_bf2(float a, float b) {
    __hip_bfloat162 t = __float22bfloat162_rn(make_float2(a, b));
    union { __hip_bfloat162 h; unsigned u; } v; v.h = t;
    return v.u;
}

// async global->LDS DMA, 16B per lane. LDS dest = wave-uniform base + lane*16.
__device__ __forceinline__ void gload16(const u16* g, u16* l) {
    __builtin_amdgcn_global_load_lds(
        (const __attribute__((address_space(1))) void*)g,
        (__attribute__((address_space(3))) void*)l, 16, 0, 0);
}

// ---------------- elementwise cast fp32 -> bf16 (vec4) ----------------
__global__ void cast_bf16_k(const float* __restrict__ in, u16* __restrict__ out, int n4) {
    int i = blockIdx.x * 256 + threadIdx.x;
    if (i >= n4) return;
    float4 v = ((const float4*)in)[i];
    u16x4 o;
    o.x = f2bf(v.x); o.y = f2bf(v.y); o.z = f2bf(v.z); o.w = f2bf(v.w);
    ((u16x4*)out)[i] = o;
}

// ------------- QKV weight transpose-cast: 3 weights in one launch -------------
__global__ void tcast3_k(const float* __restrict__ wq, const float* __restrict__ wk,
                         const float* __restrict__ wv, u16* __restrict__ out) {
    __shared__ float tile[32][33];
    int bx = blockIdx.x, by = blockIdx.y, bz = blockIdx.z;
    int which = bz >> 4, h = bz & 15;
    const float* ip = (which == 0 ? wq : which == 1 ? wk : wv) + (size_t)h * AT_M * AT_D;
    u16* op = out + ((size_t)which * AT_H + h) * AT_M * AT_D;
    int tx = threadIdx.x, ty = threadIdx.y;
    #pragma unroll
    for (int j = 0; j < 32; j += 8)
        tile[ty + j][tx] = ip[(size_t)(by * 32 + ty + j) * AT_D + bx * 32 + tx];
    __syncthreads();
    #pragma unroll
    for (int j = 0; j < 32; j += 8)
        op[(size_t)(bx * 32 + ty + j) * AT_M + by * 32 + tx] = f2bf(tile[tx][ty + j]);
}

// ------------- transpose-cast: in[R][C] fp32 -> out[C][R] bf16 (w_ao) -------------
__global__ void tcast_k(const float* __restrict__ in, u16* __restrict__ out, int R, int C) {
    __shared__ float tile[32][33];
    int bx = blockIdx.x, by = blockIdx.y;
    int tx = threadIdx.x, ty = threadIdx.y;
    #pragma unroll
    for (int j = 0; j < 32; j += 8)
        tile[ty + j][tx] = in[(size_t)(by * 32 + ty + j) * C + bx * 32 + tx];
    __syncthreads();
    #pragma unroll
    for (int j = 0; j < 32; j += 8)
        out[(size_t)(bx * 32 + ty + j) * R + by * 32 + tx] = f2bf(tile[tx][ty + j]);
}

// ------------- batched transpose bf16 -> bf16: in[bz][R][C] -> out[bz][C][R] -------------
__global__ void tbf16_k(const u16* __restrict__ in, u16* __restrict__ out, int R, int C) {
    __shared__ u16 tile[32][33];
    int bx = blockIdx.x, by = blockIdx.y, bz = blockIdx.z;
    const u16* ip = in + (size_t)bz * R * C;
    u16* op = out + (size_t)bz * R * C;
    int tx = threadIdx.x, ty = threadIdx.y;
    #pragma unroll
    for (int j = 0; j < 32; j += 8)
        tile[ty + j][tx] = ip[(size_t)(by * 32 + ty + j) * C + bx * 32 + tx];
    __syncthreads();
    #pragma unroll
    for (int j = 0; j < 32; j += 8)
        op[(size_t)(bx * 32 + ty + j) * R + by * 32 + tx] = tile[tx][ty + j];
}

// ---------------- RoPE in place; q additionally scaled by 1/128 (muP) ----------------
__global__ void rope_k(u16* __restrict__ q, u16* __restrict__ k, int total) {
    int i = blockIdx.x * 256 + threadIdx.x;
    if (i >= total) return;
    int d = i & 63;
    int rest = i >> 6;                 // (b*T+t)*H + h
    int t = (rest >> 4) & (AT_T - 1);
    size_t base = (size_t)rest * 128;
    float freq = __expf(-(float)d * (9.210340371976184f / 64.0f)); // 10000^{-d/64}
    float ang = (float)t * freq;
    float s, c;
    sincosf(ang, &s, &c);
    const float qs = 0.0078125f;  // 1/128, exact
    float qe = bf2f(q[base + d]), qo = bf2f(q[base + d + 64]);
    q[base + d]      = f2bf((qe * c - qo * s) * qs);
    q[base + d + 64] = f2bf((qe * s + qo * c) * qs);
    float ke = bf2f(k[base + d]), ko = bf2f(k[base + d + 64]);
    k[base + d]      = f2bf(ke * c - ko * s);
    k[base + d + 64] = f2bf(ke * s + ko * c);
}

// =================================================================================
// 256x256-tile 8-phase QKV GEMM (m201-template port), 512 threads, 8 waves (2Mx4N).
// Per-wave output 128x64 (8x4 frags). Per phase: one C-quadrant (16 MFMA) with
// {12 ds_read_b128 || 1 stage-unit (2 global_load_lds)} -> barrier -> lgkmcnt(0) ->
// setprio(1) MFMA setprio(0) -> [vmcnt(4) at ph4/ph8 only] -> barrier.
// Stage units are the quadrant-striped row-sets (A-unit u: rows [64u,+64)U[128+64u,+64);
// B-unit u: four 32-row stripes), each issued the phase AFTER its LDS region dies.
// Counted vmcnt(4): 2 units always in flight across barriers; never drains mid-loop.
// LDS 128 KiB (2 buf x (A 256x64 + B 256x64) bf16), chunk-XOR swizzle as before.
// =================================================================================
#define BUFSZ 32768   // u16 per buffer (A 16384 + B 16384)

#define SBAR do { asm volatile("" ::: "memory"); __builtin_amdgcn_s_barrier(); asm volatile("" ::: "memory"); } while(0)
#define LGKM0 asm volatile("s_waitcnt lgkmcnt(0)" ::: "memory")
#define VM4 asm volatile("s_waitcnt vmcnt(4)" ::: "memory")
#define VM0 asm volatile("s_waitcnt vmcnt(0)" ::: "memory")
#define SP1 __builtin_amdgcn_s_setprio(1)
#define SP0 __builtin_amdgcn_s_setprio(0)

// stage A-unit u of the k-tile at elem-offset kk into buffer buf (2 gloads)
#define STAGE_A(buf, u, kk) do { \
    gload16(gaQ + (size_t)((u)*64)*K + (kk),       smem + (buf)*BUFSZ + ((u)*64 + wave*8)*64); \
    gload16(gaQ + (size_t)((u)*64 + 128)*K + (kk), smem + (buf)*BUFSZ + ((u)*64 + 128 + wave*8)*64); \
} while(0)
#define STAGE_B(buf, u, kk) do { \
    gload16(gbQ + (size_t)((u)*32)*K + (kk),       smem + (buf)*BUFSZ + 16384 + ((u)*32 + bwrow)*64); \
    gload16(gbQ + (size_t)((u)*32 + 128)*K + (kk), smem + (buf)*BUFSZ + 16384 + ((u)*32 + 128 + bwrow)*64); \
} while(0)

template<int QM, int QN>
__device__ __forceinline__ void ph_read(const u16* __restrict__ as_, const u16* __restrict__ bs_,
        short8 (&af_)[4][2], short8 (&bf_)[2][2], int wr, int wc, int quad, int l16, int rsw) {
    #pragma unroll
    for (int f = 0; f < 4; ++f)
        #pragma unroll
        for (int ks = 0; ks < 2; ++ks)
            af_[f][ks] = *(const short8*)&as_[(wr*128 + (QM*4+f)*16 + l16)*64 + (((ks*4+quad)^rsw)*8)];
    #pragma unroll
    for (int g = 0; g < 2; ++g)
        #pragma unroll
        for (int ks = 0; ks < 2; ++ks)
            bf_[g][ks] = *(const short8*)&bs_[(wc*64 + (QN*2+g)*16 + l16)*64 + (((ks*4+quad)^rsw)*8)];
}

template<int QM, int QN>
__device__ __forceinline__ void ph_mfma(f32x4 (&acc)[8][4],
        const short8 (&af_)[4][2], const short8 (&bf_)[2][2]) {
    #pragma unroll
    for (int ks = 0; ks < 2; ++ks)
        #pragma unroll
        for (int f = 0; f < 4; ++f)
            #pragma unroll
            for (int g = 0; g < 2; ++g)
                acc[QM*4+f][QN*2+g] = __builtin_amdgcn_mfma_f32_16x16x32_bf16(
                    af_[f][ks], bf_[g][ks], acc[QM*4+f][QN*2+g], 0, 0, 0);
}

__global__ __launch_bounds__(512, 2) void gemm256_8ph_k(
    const u16* __restrict__ A, const u16* __restrict__ Bt, u16* __restrict__ Cv,
    int M, int N, int K)
{
    __shared__ __align__(1024) u16 smem[2 * BUFSZ];   // 128 KiB
    const int tid  = threadIdx.x;
    const int wave = tid >> 6, lane = tid & 63;
    const int quad = lane >> 4, l16 = lane & 15;
    const int wr = wave >> 2, wc = wave & 3;
    const int srl = lane >> 3;              // 0..7
    const int jc  = (lane & 7) ^ srl;       // pre-swizzled source k-chunk
    const int bwrow = wr * 64 + wc * 8;     // wave-part of B staging row
    const int rsw = l16 & 7;

    // bijective XCD-aware block swizzle (total = 384, 384 % 8 == 0)
    const int nbx = N >> 8;
    const int total = (M >> 8) * nbx;
    const int cpx = total >> 3;
    int l = blockIdx.y * nbx + blockIdx.x;
    int ls = (l & 7) * cpx + (l >> 3);
    const int m0 = (ls / nbx) * 256, n0 = (ls % nbx) * 256;

    const u16* gaQ = A  + (size_t)(m0 + wave * 8 + srl) * K + jc * 8;
    const u16* gbQ = Bt + (size_t)(n0 + bwrow + srl) * K + jc * 8;

    f32x4 zero = {0.f, 0.f, 0.f, 0.f};
    f32x4 acc[8][4];
    #pragma unroll
    for (int i = 0; i < 8; i++)
        #pragma unroll
        for (int j = 0; j < 4; j++) acc[i][j] = zero;

    // prologue: tile0 complete (8 loads) + tile1 units A0,B0 (4 loads); wait tile0 only
    STAGE_A(0, 0, 0); STAGE_B(0, 0, 0); STAGE_A(0, 1, 0); STAGE_B(0, 1, 0);
    STAGE_A(1, 0, 64); STAGE_B(1, 0, 64);
    VM4; SBAR;

    const u16* a0 = smem;            const u16* b0 = smem + 16384;
    const u16* a1 = smem + BUFSZ;    const u16* b1 = smem + BUFSZ + 16384;
    short8 af[4][2], bfv[2][2];

    const int NIT = K >> 7;   // 2 K-tiles per iteration
    #pragma unroll 1
    for (int it = 0; it < NIT; ++it) {
        const int ta = it * 2;
        const bool more = (it + 1 < NIT);
        const int ka1 = (ta + 1) * 64, ka2 = (ta + 2) * 64, ka3 = (ta + 3) * 64;

        // ---- ph1: quadrant (0,0) of tile ta (buf0); stage buf1.Au1 <- tile ta+1
        ph_read<0,0>(a0, b0, af, bfv, wr, wc, quad, l16, rsw);
        STAGE_A(1, 1, ka1);
        SBAR; LGKM0; SP1; ph_mfma<0,0>(acc, af, bfv); SP0; SBAR;
        // ---- ph2: (0,1); stage buf1.Bu1 <- tile ta+1
        ph_read<0,1>(a0, b0, af, bfv, wr, wc, quad, l16, rsw);
        STAGE_B(1, 1, ka1);
        SBAR; LGKM0; SP1; ph_mfma<0,1>(acc, af, bfv); SP0; SBAR;
        // ---- ph3: (1,0); stage buf0.Au0 <- tile ta+2 (Au0 dead since ph2)
        ph_read<1,0>(a0, b0, af, bfv, wr, wc, quad, l16, rsw);
        if (more) STAGE_A(0, 0, ka2);
        SBAR; LGKM0; SP1; ph_mfma<1,0>(acc, af, bfv); SP0; SBAR;
        // ---- ph4: (1,1); stage buf0.Bu0; counted vmcnt -> tile ta+1 fully landed
        ph_read<1,1>(a0, b0, af, bfv, wr, wc, quad, l16, rsw);
        if (more) STAGE_B(0, 0, ka2);
        SBAR; LGKM0; SP1; ph_mfma<1,1>(acc, af, bfv); SP0;
        if (more) { VM4; } else { VM0; }
        SBAR;
        // ---- ph5: quadrant (0,0) of tile ta+1 (buf1); stage buf0.Au1 <- ta+2
        ph_read<0,0>(a1, b1, af, bfv, wr, wc, quad, l16, rsw);
        if (more) STAGE_A(0, 1, ka2);
        SBAR; LGKM0; SP1; ph_mfma<0,0>(acc, af, bfv); SP0; SBAR;
        // ---- ph6: (0,1); stage buf0.Bu1 <- ta+2
        ph_read<0,1>(a1, b1, af, bfv, wr, wc, quad, l16, rsw);
        if (more) STAGE_B(0, 1, ka2);
        SBAR; LGKM0; SP1; ph_mfma<0,1>(acc, af, bfv); SP0; SBAR;
        // ---- ph7: (1,0); stage buf1.Au0 <- tile ta+3 (buf1.Au0 dead since ph6)
        ph_read<1,0>(a1, b1, af, bfv, wr, wc, quad, l16, rsw);
        if (more) STAGE_A(1, 0, ka3);
        SBAR; LGKM0; SP1; ph_mfma<1,0>(acc, af, bfv); SP0; SBAR;
        // ---- ph8: (1,1); stage buf1.Bu0 <- ta+3; counted vmcnt -> tile ta+2 landed
        ph_read<1,1>(a1, b1, af, bfv, wr, wc, quad, l16, rsw);
        if (more) STAGE_B(1, 0, ka3);
        SBAR; LGKM0; SP1; ph_mfma<1,1>(acc, af, bfv); SP0;
        if (more) { VM4; } else { VM0; }
        SBAR;
    }

    // epilogue: segmented bf16 store (q|k|v each [M][2048])
    #pragma unroll
    for (int mf = 0; mf < 8; ++mf)
        #pragma unroll
        for (int nf = 0; nf < 4; ++nf) {
            int col = n0 + wc * 64 + nf * 16 + l16;
            size_t base = ((size_t)(col >> 11) * M) * 2048 + (col & 2047);
            #pragma unroll
            for (int r = 0; r < 4; ++r) {
                int row = m0 + wr * 128 + mf * 16 + quad * 4 + r;
                Cv[base + (size_t)row * 2048] = f2bf(acc[mf][nf][r]);
            }
        }
}

// ---------------- GEMM: C[M][N] = A[M][K] * Bt[N][K]^T  (bf16 in, fp32 acc) ----------------
// 128^2 tile, register-staged, XOR-swizzled LDS. Kept for the output projection
// (N=2048 -> 256-tile grid would be only 128 blocks; 512 blocks here).
template<int FP32OUT>
__global__ __launch_bounds__(256, 2) void gemm_bt_k(
    const u16* __restrict__ A, const u16* __restrict__ Bt, void* __restrict__ Cv,
    int M, int N, int K)
{
    __shared__ u16 As[128 * 64];
    __shared__ u16 Bs[128 * 64];
    const int tid = threadIdx.x, wave = tid >> 6, lane = tid & 63;
    const int quad = lane >> 4, l16 = lane & 15;
    const int m0 = blockIdx.y * 128, n0 = blockIdx.x * 128;
    const int mw = (wave & 1) * 64, nw = (wave >> 1) * 64;

    f32x4 zero = {0.f, 0.f, 0.f, 0.f};
    f32x4 acc[4][4];
    #pragma unroll
    for (int i = 0; i < 4; i++)
        #pragma unroll
        for (int j = 0; j < 4; j++) acc[i][j] = zero;

    const int sr = tid >> 3;          // 0..31
    const int sj = tid & 7;           // k-chunk
    const u16* ga0 = A  + (size_t)(m0 + sr) * K + sj * 8;
    const u16* gb0 = Bt + (size_t)(n0 + sr) * K + sj * 8;
    int woff[4];
    #pragma unroll
    for (int it = 0; it < 4; ++it) {
        int r = it * 32 + sr;
        woff[it] = r * 64 + ((sj ^ (r & 7)) * 8);
    }

    short8 abuf[4], bbuf[4];
    #pragma unroll
    for (int it = 0; it < 4; ++it) {
        abuf[it] = *(const short8*)(ga0 + (size_t)(it * 32) * K);
        bbuf[it] = *(const short8*)(gb0 + (size_t)(it * 32) * K);
    }
    #pragma unroll
    for (int it = 0; it < 4; ++it) {
        *(short8*)&As[woff[it]] = abuf[it];
        *(short8*)&Bs[woff[it]] = bbuf[it];
    }
    __syncthreads();

    const int rsw = l16 & 7;

    for (int kk = 0; kk < K; kk += 64) {
        const bool pre = (kk + 64 < K);
        if (pre) {
            #pragma unroll
            for (int it = 0; it < 4; ++it) {
                abuf[it] = *(const short8*)(ga0 + (size_t)(it * 32) * K + (kk + 64));
                bbuf[it] = *(const short8*)(gb0 + (size_t)(it * 32) * K + (kk + 64));
            }
        }
        #pragma unroll
        for (int ks = 0; ks < 2; ks++) {
            const int ch = ((ks * 4 + quad) ^ rsw) * 8;
            short8 af[4], bfr[4];
            #pragma unroll
            for (int mf = 0; mf < 4; mf++)
                af[mf] = *(const short8*)&As[(mw + mf * 16 + l16) * 64 + ch];
            #pragma unroll
            for (int nf = 0; nf < 4; nf++)
                bfr[nf] = *(const short8*)&Bs[(nw + nf * 16 + l16) * 64 + ch];
            #pragma unroll
            for (int mf = 0; mf < 4; mf++)
                #pragma unroll
                for (int nf = 0; nf < 4; nf++)
                    acc[mf][nf] = __builtin_amdgcn_mfma_f32_16x16x32_bf16(af[mf], bfr[nf], acc[mf][nf], 0, 0, 0);
        }
        if (pre) {
            __syncthreads();
            #pragma unroll
            for (int it = 0; it < 4; ++it) {
                *(short8*)&As[woff[it]] = abuf[it];
                *(short8*)&Bs[woff[it]] = bbuf[it];
            }
            __syncthreads();
        }
    }

    #pragma unroll
    for (int mf = 0; mf < 4; mf++)
        #pragma unroll
        for (int nf = 0; nf < 4; nf++)
            #pragma unroll
            for (int r = 0; r < 4; r++) {
                int row = m0 + mw + mf * 16 + quad * 4 + r;
                int col = n0 + nw + nf * 16 + l16;
                if (FP32OUT) ((float*)Cv)[(size_t)row * N + col] = acc[mf][nf][r];
                else         ((u16*) Cv)[(size_t)row * N + col] = f2bf(acc[mf][nf][r]);
            }
}

// ---------------- Flash attention, causal, paired complementary 64-row subtiles ----------------
__global__ __launch_bounds__(256, 2) void attn_k(
    const u16* __restrict__ q, const u16* __restrict__ k,
    const u16* __restrict__ vt, u16* __restrict__ o)
{
    __shared__ __align__(16) u16 Ks[64 * 132];   // [key][d], pad 4
    __shared__ __align__(16) u16 Vs[128 * 68];   // [d][key], pad 4 (= V^T)
    __shared__ __align__(16) u16 Pt[128 * 68];   // [qrow_local][key], pad 4
    const int tid = threadIdx.x, wave = tid >> 6, lane = tid & 63;
    const int quad = lane >> 4, l16 = lane & 15;
    const int h = blockIdx.y, b = blockIdx.z;
    const int p = (b & 1) ? (15 - (int)blockIdx.x) : (int)blockIdx.x;
    const int sub0 = p, sub1 = 31 - p;
    const int nkt = 32 - p;

    const int krow = tid >> 4, kc8 = tid & 15;
    const int vd   = tid >> 3, vc8 = tid & 7;
    const u16* kgp = k  + ((size_t)(b * AT_T) * AT_H + h) * 128;
    const u16* vgp = vt + ((size_t)(b * AT_H + h) * 128) * (size_t)AT_T;

    short8 qf[2][4];
    #pragma unroll
    for (int mf = 0; mf < 2; mf++) {
        int row = (mf ? sub1 : sub0) * 64 + wave * 16 + l16;
        const u16* qp = q + ((size_t)(b * AT_T + row) * AT_H + h) * 128 + quad * 8;
        #pragma unroll
        for (int ks = 0; ks < 4; ks++)
            qf[mf][ks] = *(const short8*)(qp + ks * 32);
    }

    f32x4 zero = {0.f, 0.f, 0.f, 0.f};
    f32x4 Oacc[2][8];
    #pragma unroll
    for (int i = 0; i < 2; i++)
        #pragma unroll
        for (int j = 0; j < 8; j++) Oacc[i][j] = zero;
    float l_i[2] = {0.f, 0.f};

    short8 kreg[4], vreg[4];
    #pragma unroll
    for (int it = 0; it < 4; ++it) {
        kreg[it] = *(const short8*)(kgp + (size_t)(krow + it * 16) * 2048 + kc8 * 8);
        vreg[it] = *(const short8*)(vgp + (size_t)(vd + it * 32) * AT_T + vc8 * 8);
    }
    #pragma unroll
    for (int it = 0; it < 4; ++it) {
        *(short8*)&Ks[(krow + it * 16) * 132 + kc8 * 8] = kreg[it];
        *(short8*)&Vs[(vd + it * 32) * 68 + vc8 * 8] = vreg[it];
    }
    __syncthreads();

    for (int kt = 0; kt < nkt; ++kt) {
        const bool pre = (kt + 1 < nkt);
        if (pre) {
            #pragma unroll
            for (int it = 0; it < 4; ++it) {
                kreg[it] = *(const short8*)(kgp + (size_t)((kt + 1) * 64 + krow + it * 16) * 2048 + kc8 * 8);
                vreg[it] = *(const short8*)(vgp + (size_t)(vd + it * 32) * AT_T + (kt + 1) * 64 + vc8 * 8);
            }
        }
        const bool actA = (kt <= sub0);

        f32x4 St[4][2];
        #pragma unroll
        for (int mt = 0; mt < 4; mt++) { St[mt][0] = zero; St[mt][1] = zero; }
        #pragma unroll
        for (int mt = 0; mt < 4; mt++) {
            short8 af[4];
            #pragma unroll
            for (int ks = 0; ks < 4; ks++)
                af[ks] = *(const short8*)&Ks[(mt * 16 + l16) * 132 + ks * 32 + quad * 8];
            #pragma unroll
            for (int ks = 0; ks < 4; ks++)
                St[mt][1] = __builtin_amdgcn_mfma_f32_16x16x32_bf16(af[ks], qf[1][ks], St[mt][1], 0, 0, 0);
            if (actA) {
                #pragma unroll
                for (int ks = 0; ks < 4; ks++)
                    St[mt][0] = __builtin_amdgcn_mfma_f32_16x16x32_bf16(af[ks], qf[0][ks], St[mt][0], 0, 0, 0);
            }
        }

        #pragma unroll
        for (int mf = 0; mf < 2; mf++) {
            if (mf == 0 && !actA) continue;
            const int sub = mf ? sub1 : sub0;
            if (kt == sub) {
                int qrow = sub * 64 + wave * 16 + l16;
                #pragma unroll
                for (int mt = 0; mt < 4; mt++)
                    #pragma unroll
                    for (int r = 0; r < 4; r++) {
                        int key = kt * 64 + mt * 16 + quad * 4 + r;
                        if (key > qrow) St[mt][mf][r] = -1e30f;
                    }
            }
            float rs = 0.f;
            #pragma unroll
            for (int mt = 0; mt < 4; mt++)
                #pragma unroll
                for (int r = 0; r < 4; r++) {
                    float pv = __expf(St[mt][mf][r]);
                    St[mt][mf][r] = pv;
                    rs += pv;
                }
            rs += __shfl_xor(rs, 16, 64);
            rs += __shfl_xor(rs, 32, 64);
            l_i[mf] += rs;
            u16* pp = &Pt[(mf * 64 + wave * 16 + l16) * 68 + quad * 4];
            #pragma unroll
            for (int mt = 0; mt < 4; mt++) {
                *(unsigned*)(pp + mt * 16)     = pack_bf2(St[mt][mf][0], St[mt][mf][1]);
                *(unsigned*)(pp + mt * 16 + 2) = pack_bf2(St[mt][mf][2], St[mt][mf][3]);
            }
        }

        short8 pf[2][2];
        #pragma unroll
        for (int mf = 0; mf < 2; mf++)
            #pragma unroll
            for (int ks = 0; ks < 2; ks++)
                pf[mf][ks] = *(const short8*)&Pt[(mf * 64 + wave * 16 + l16) * 68 + ks * 32 + quad * 8];

        #pragma unroll
        for (int mt = 0; mt < 8; mt++) {
            short8 vf[2];
            #pragma unroll
            for (int ks = 0; ks < 2; ks++)
                vf[ks] = *(const short8*)&Vs[(mt * 16 + l16) * 68 + ks * 32 + quad * 8];
            #pragma unroll
            for (int ks = 0; ks < 2; ks++) {
                Oacc[1][mt] = __builtin_amdgcn_mfma_f32_16x16x32_bf16(vf[ks], pf[1][ks], Oacc[1][mt], 0, 0, 0);
                if (actA)
                    Oacc[0][mt] = __builtin_amdgcn_mfma_f32_16x16x32_bf16(vf[ks], pf[0][ks], Oacc[0][mt], 0, 0, 0);
            }
        }

        __syncthreads();
        if (pre) {
            #pragma unroll
            for (int it = 0; it < 4; ++it) {
                *(short8*)&Ks[(krow + it * 16) * 132 + kc8 * 8] = kreg[it];
                *(short8*)&Vs[(vd + it * 32) * 68 + vc8 * 8] = vreg[it];
            }
        }
        __syncthreads();
    }

    #pragma unroll
    for (int mf = 0; mf < 2; mf++) {
        float inv = 1.0f / l_i[mf];
        int row = (mf ? sub1 : sub0) * 64 + wave * 16 + l16;
        u16* op = o + ((size_t)(b * AT_T + row) * AT_H + h) * 128 + quad * 4;
        #pragma unroll
        for (int mt = 0; mt < 8; mt++) {
            *(unsigned*)(op + mt * 16)     = pack_bf2(Oacc[mf][mt][0] * inv, Oacc[mf][mt][1] * inv);
            *(unsigned*)(op + mt * 16 + 2) = pack_bf2(Oacc[mf][mt][2] * inv, Oacc[mf][mt][3] * inv);
        }
    }
}

// ---------------- launch ----------------
extern "C" void kernel_launch(void* const* d_in, const int* in_sizes, int n_in,
                              void* d_out, int out_size, void* d_ws, size_t ws_size,
                              hipStream_t stream) {
    const float* x    = (const float*)d_in[0];
    const float* w_aq = (const float*)d_in[1];
    const float* w_ak = (const float*)d_in[2];
    const float* w_av = (const float*)d_in[3];
    const float* w_ao = (const float*)d_in[4];
    float* outp = (float*)d_out;

    u16* ws   = (u16*)d_ws;
    u16* xb   = ws;                           // [4096][2048]      x, bf16
    u16* wqb  = xb   + (size_t)NROW * HD;     // [6144 n][2048 k]  (wq|wk|wv transposed)
    u16* waob = wqb  + (size_t)3 * HD * AT_M; // [2048 m][2048 hd] (w_ao^T)
    u16* qb   = waob + (size_t)HD * AT_M;     // [B,T,H,D] (then kb, vb contiguous)
    u16* kb   = qb   + (size_t)NROW * HD;
    u16* vb   = kb   + (size_t)NROW * HD;
    u16* vtb  = vb   + (size_t)NROW * HD;     // [B,H,D,T]
    u16* ob   = xb;                           // alias: xb dead after projections

    // 1) casts / transposes
    cast_bf16_k<<<(NROW * HD / 4 + 255) / 256, 256, 0, stream>>>(x, xb, NROW * HD / 4);
    dim3 tb(32, 8);
    tcast3_k<<<dim3(AT_D / 32, AT_M / 32, 48), tb, 0, stream>>>(w_aq, w_ak, w_av, wqb);
    tcast_k<<<dim3(AT_M / 32, HD / 32), tb, 0, stream>>>(w_ao, waob, HD, AT_M);

    // 2) fused QKV projection: 256^2 8-phase, grid 24x16 = 384 blocks
    gemm256_8ph_k<<<dim3(3 * HD / 256, NROW / 256), 512, 0, stream>>>(xb, wqb, qb, NROW, 3 * HD, AT_M);

    // 3) RoPE on q,k (q scaled by 1/128)
    rope_k<<<(NROW * AT_H * 64 + 255) / 256, 256, 0, stream>>>(qb, kb, NROW * AT_H * 64);

    // 4) v -> [B,H,D,T]
    tbf16_k<<<dim3(HD / 32, AT_T / 32, AT_B), tb, 0, stream>>>(vb, vtb, AT_T, HD);

    // 5) attention (paired complementary subtiles, prefetch, max-free softmax)
    attn_k<<<dim3(16, AT_H, AT_B), 256, 0, stream>>>(qb, kb, vtb, ob);

    // 6) output projection (fp32 out)
    gemm_bt_k<1><<<dim3(AT_M / 128, NROW / 128), 256, 0, stream>>>(ob, waob, outp, NROW, AT_M, HD);
}

// Round 5
// 401.882 us; speedup vs baseline: 1.0253x; 1.0253x over previous
//
#include <hip/hip_runtime.h>
#include <hip/hip_bf16.h>
#include <cmath>

typedef unsigned short u16;
typedef __attribute__((ext_vector_type(8))) short short8;
typedef __attribute__((ext_vector_type(4))) float f32x4;
typedef __attribute__((ext_vector_type(4))) unsigned short u16x4;

#define AT_B 2
#define AT_T 2048
#define AT_H 16
#define AT_D 128
#define AT_M 2048
#define NROW (AT_B*AT_T)   // 4096
#define HD   (AT_H*AT_D)   // 2048

__device__ __forceinline__ u16 f2bf(float f) {
    union { float f; unsigned u; } v; v.f = f;
    unsigned u = v.u;
    unsigned r = u + 0x7fffu + ((u >> 16) & 1u);
    return (u16)(r >> 16);
}
__device__ __forceinline__ float bf2f(u16 h) {
    union { unsigned u; float f; } v; v.u = ((unsigned)h) << 16;
    return v.f;
}
__device__ __forceinline__ unsigned pack_bf2(float a, float b) {
    __hip_bfloat162 t = __float22bfloat162_rn(make_float2(a, b));
    union { __hip_bfloat162 h; unsigned u; } v; v.h = t;
    return v.u;
}

// async global->LDS DMA, 16B per lane. LDS dest = wave-uniform base + lane*16.
__device__ __forceinline__ void gload16(const u16* g, u16* l) {
    __builtin_amdgcn_global_load_lds(
        (const __attribute__((address_space(1))) void*)g,
        (__attribute__((address_space(3))) void*)l, 16, 0, 0);
}

// ---------------- elementwise cast fp32 -> bf16 (vec4) ----------------
__global__ void cast_bf16_k(const float* __restrict__ in, u16* __restrict__ out, int n4) {
    int i = blockIdx.x * 256 + threadIdx.x;
    if (i >= n4) return;
    float4 v = ((const float4*)in)[i];
    u16x4 o;
    o.x = f2bf(v.x); o.y = f2bf(v.y); o.z = f2bf(v.z); o.w = f2bf(v.w);
    ((u16x4*)out)[i] = o;
}

// ------------- QKV weight transpose-cast: 3 weights in one launch -------------
__global__ void tcast3_k(const float* __restrict__ wq, const float* __restrict__ wk,
                         const float* __restrict__ wv, u16* __restrict__ out) {
    __shared__ float tile[32][33];
    int bx = blockIdx.x, by = blockIdx.y, bz = blockIdx.z;
    int which = bz >> 4, h = bz & 15;
    const float* ip = (which == 0 ? wq : which == 1 ? wk : wv) + (size_t)h * AT_M * AT_D;
    u16* op = out + ((size_t)which * AT_H + h) * AT_M * AT_D;
    int tx = threadIdx.x, ty = threadIdx.y;
    #pragma unroll
    for (int j = 0; j < 32; j += 8)
        tile[ty + j][tx] = ip[(size_t)(by * 32 + ty + j) * AT_D + bx * 32 + tx];
    __syncthreads();
    #pragma unroll
    for (int j = 0; j < 32; j += 8)
        op[(size_t)(bx * 32 + ty + j) * AT_M + by * 32 + tx] = f2bf(tile[tx][ty + j]);
}

// ------------- transpose-cast: in[R][C] fp32 -> out[C][R] bf16 (w_ao) -------------
__global__ void tcast_k(const float* __restrict__ in, u16* __restrict__ out, int R, int C) {
    __shared__ float tile[32][33];
    int bx = blockIdx.x, by = blockIdx.y;
    int tx = threadIdx.x, ty = threadIdx.y;
    #pragma unroll
    for (int j = 0; j < 32; j += 8)
        tile[ty + j][tx] = in[(size_t)(by * 32 + ty + j) * C + bx * 32 + tx];
    __syncthreads();
    #pragma unroll
    for (int j = 0; j < 32; j += 8)
        out[(size_t)(bx * 32 + ty + j) * R + by * 32 + tx] = f2bf(tile[tx][ty + j]);
}

// ------------- batched transpose bf16 -> bf16: in[bz][R][C] -> out[bz][C][R] -------------
__global__ void tbf16_k(const u16* __restrict__ in, u16* __restrict__ out, int R, int C) {
    __shared__ u16 tile[32][33];
    int bx = blockIdx.x, by = blockIdx.y, bz = blockIdx.z;
    const u16* ip = in + (size_t)bz * R * C;
    u16* op = out + (size_t)bz * R * C;
    int tx = threadIdx.x, ty = threadIdx.y;
    #pragma unroll
    for (int j = 0; j < 32; j += 8)
        tile[ty + j][tx] = ip[(size_t)(by * 32 + ty + j) * C + bx * 32 + tx];
    __syncthreads();
    #pragma unroll
    for (int j = 0; j < 32; j += 8)
        op[(size_t)(bx * 32 + ty + j) * R + by * 32 + tx] = tile[tx][ty + j];
}

// ---------------- RoPE in place; q additionally scaled by 1/128 (muP) ----------------
__global__ void rope_k(u16* __restrict__ q, u16* __restrict__ k, int total) {
    int i = blockIdx.x * 256 + threadIdx.x;
    if (i >= total) return;
    int d = i & 63;
    int rest = i >> 6;                 // (b*T+t)*H + h
    int t = (rest >> 4) & (AT_T - 1);
    size_t base = (size_t)rest * 128;
    float freq = __expf(-(float)d * (9.210340371976184f / 64.0f)); // 10000^{-d/64}
    float ang = (float)t * freq;
    float s, c;
    sincosf(ang, &s, &c);
    const float qs = 0.0078125f;  // 1/128, exact
    float qe = bf2f(q[base + d]), qo = bf2f(q[base + d + 64]);
    q[base + d]      = f2bf((qe * c - qo * s) * qs);
    q[base + d + 64] = f2bf((qe * s + qo * c) * qs);
    float ke = bf2f(k[base + d]), ko = bf2f(k[base + d + 64]);
    k[base + d]      = f2bf(ke * c - ko * s);
    k[base + d + 64] = f2bf(ke * s + ko * c);
}

// =================================================================================
// 256x256 8-phase QKV GEMM v2 (gray-code quadrants, liveness-exact staging).
// 512 threads = 8 waves (2M x 4N), per-wave output 128x64 (acc[8][4]).
// Per K-tile (BK=64), 4 phases in gray-code (0,0)->(0,1)->(1,1)->(1,0):
//   P1: ds-read A0(12 w/ B0) || stage B0(t+1) -> bar,lgkm0,MFMA(0,0) -> bar
//   P2: ds-read B1 (4)       || stage A0(t+2) -> bar,lgkm0,MFMA(0,1) [A0 in regs]
//   P3: ds-read A1 (8)       || stage B1(t+2) -> bar,lgkm0,MFMA(1,1) [B1 in regs]
//   P4: ds-read B0 (4)       || stage A1(t+2) -> bar,lgkm0,MFMA(1,0), VM6 -> bar
// Stage units match quadrant liveness EXACTLY (A-unit u = rows u*64+[0,64)U128+...;
// B-unit u = cols {wc*64+u*32+[0,32)}), each staged one barrier after its region's
// last ds_read retires -> no DS-vs-DMA ordering race. vmcnt(6) = 3 units in flight
// across the tile boundary (FIFO: the wait at t.P4 retires all 8 loads of tile t+1).
// 28 ds_read_b128 / wave / K-tile (was 48). No XCD swizzle (R4's doubled FETCH).
// =================================================================================
#define BUFSZ 32768   // u16 per buffer (A 16384 + B 16384)

#define SBAR do { asm volatile("" ::: "memory"); __builtin_amdgcn_s_barrier(); asm volatile("" ::: "memory"); } while(0)
#define LGKM0 asm volatile("s_waitcnt lgkmcnt(0)" ::: "memory")
#define VM6 asm volatile("s_waitcnt vmcnt(6)" ::: "memory")
#define VM0 asm volatile("s_waitcnt vmcnt(0)" ::: "memory")
#define SP1 __builtin_amdgcn_s_setprio(1)
#define SP0 __builtin_amdgcn_s_setprio(0)

// A-unit u: global rows u*64+[0,64) and u*64+128+[0,64); 2 gloads/wave
#define STAGE_A(buf, u, kk) do { \
    gload16(gaQ + (size_t)((u)*64)*K + (kk),       smem + (buf)*BUFSZ + ((u)*64 + wave*8)*64); \
    gload16(gaQ + (size_t)((u)*64 + 128)*K + (kk), smem + (buf)*BUFSZ + ((u)*64 + 128 + wave*8)*64); \
} while(0)
// B-unit u: global rows wc*64 + u*32 + wr*16 + {0,8} + srl; 2 gloads/wave
#define STAGE_B(buf, u, kk) do { \
    gload16(gbQ + (size_t)((u)*32)*K + (kk),     smem + (buf)*BUFSZ + 16384 + (wc*64 + (u)*32 + wr*16)*64); \
    gload16(gbQ + (size_t)((u)*32 + 8)*K + (kk), smem + (buf)*BUFSZ + 16384 + (wc*64 + (u)*32 + wr*16 + 8)*64); \
} while(0)

__device__ __forceinline__ void read_Afr(const u16* __restrict__ as_, short8 (&af_)[4][2],
        int qm, int wr, int quad, int l16, int rsw) {
    #pragma unroll
    for (int f = 0; f < 4; ++f)
        #pragma unroll
        for (int ks = 0; ks < 2; ++ks)
            af_[f][ks] = *(const short8*)&as_[(wr*128 + qm*64 + f*16 + l16)*64 + (((ks*4+quad)^rsw)*8)];
}
__device__ __forceinline__ void read_Bfr(const u16* __restrict__ bs_, short8 (&bf_)[2][2],
        int qn, int wc, int quad, int l16, int rsw) {
    #pragma unroll
    for (int g = 0; g < 2; ++g)
        #pragma unroll
        for (int ks = 0; ks < 2; ++ks)
            bf_[g][ks] = *(const short8*)&bs_[(wc*64 + qn*32 + g*16 + l16)*64 + (((ks*4+quad)^rsw)*8)];
}

template<int QM, int QN>
__device__ __forceinline__ void mfma_q(f32x4 (&acc)[8][4],
        const short8 (&af_)[4][2], const short8 (&bf_)[2][2]) {
    #pragma unroll
    for (int ks = 0; ks < 2; ++ks)
        #pragma unroll
        for (int f = 0; f < 4; ++f)
            #pragma unroll
            for (int g = 0; g < 2; ++g)
                acc[QM*4+f][QN*2+g] = __builtin_amdgcn_mfma_f32_16x16x32_bf16(
                    af_[f][ks], bf_[g][ks], acc[QM*4+f][QN*2+g], 0, 0, 0);
}

__global__ __launch_bounds__(512, 2) void gemm256_8ph_k(
    const u16* __restrict__ A, const u16* __restrict__ Bt, u16* __restrict__ Cv,
    int M, int N, int K)
{
    __shared__ __align__(1024) u16 smem[2 * BUFSZ];   // 128 KiB
    const int tid  = threadIdx.x;
    const int wave = tid >> 6, lane = tid & 63;
    const int quad = lane >> 4, l16 = lane & 15;
    const int wr = wave >> 2, wc = wave & 3;
    const int srl = lane >> 3;              // 0..7
    const int jc  = (lane & 7) ^ srl;       // pre-swizzled source k-chunk
    const int rsw = l16 & 7;

    const int m0 = blockIdx.y * 256, n0 = blockIdx.x * 256;

    const u16* gaQ = A  + (size_t)(m0 + wave * 8 + srl) * K + jc * 8;
    const u16* gbQ = Bt + (size_t)(n0 + wc * 64 + wr * 16 + srl) * K + jc * 8;

    f32x4 zero = {0.f, 0.f, 0.f, 0.f};
    f32x4 acc[8][4];
    #pragma unroll
    for (int i = 0; i < 8; i++)
        #pragma unroll
        for (int j = 0; j < 4; j++) acc[i][j] = zero;

    const int NT = K >> 6;

    // prologue: all of tile0 (8 loads), then tile1's A0,B1,A1 (6 loads; B0(1) staged at t0.P1)
    STAGE_A(0, 0, 0); STAGE_B(0, 0, 0); STAGE_B(0, 1, 0); STAGE_A(0, 1, 0);
    STAGE_A(1, 0, 64); STAGE_B(1, 1, 64); STAGE_A(1, 1, 64);
    VM6;   // tile0's 8 loads landed
    SBAR;

    short8 af[4][2], bfv[2][2];

    #pragma unroll 1
    for (int t = 0; t < NT; ++t) {
        const int cb = t & 1, ob = (t + 1) & 1;
        const u16* as = smem + cb * BUFSZ;
        const u16* bs = as + 16384;
        const int k1 = (t + 1) << 6, k2 = (t + 2) << 6;
        const bool s1 = (t + 1 < NT), s2 = (t + 2 < NT);

        // ---- P1: quadrant (0,0); stage B0(t+1) into other buffer (dead since t-1.P4)
        read_Afr(as, af, 0, wr, quad, l16, rsw);
        read_Bfr(bs, bfv, 0, wc, quad, l16, rsw);
        if (s1) STAGE_B(ob, 0, k1);
        SBAR; LGKM0; SP1; mfma_q<0,0>(acc, af, bfv); SP0; SBAR;

        // ---- P2: quadrant (0,1); A0 held in regs; stage A0(t+2) (A0 LDS dead after P1)
        read_Bfr(bs, bfv, 1, wc, quad, l16, rsw);
        if (s2) STAGE_A(cb, 0, k2);
        SBAR; LGKM0; SP1; mfma_q<0,1>(acc, af, bfv); SP0; SBAR;

        // ---- P3: quadrant (1,1); B1 held in regs; stage B1(t+2) (B1 LDS dead after P2)
        read_Afr(as, af, 1, wr, quad, l16, rsw);
        if (s2) STAGE_B(cb, 1, k2);
        SBAR; LGKM0; SP1; mfma_q<1,1>(acc, af, bfv); SP0; SBAR;

        // ---- P4: quadrant (1,0); re-read B0; stage A1(t+2) (A1 LDS dead after P3)
        read_Bfr(bs, bfv, 0, wc, quad, l16, rsw);
        if (s2) STAGE_A(cb, 1, k2);
        SBAR; LGKM0; SP1; mfma_q<1,0>(acc, af, bfv); SP0;
        if (s2)      { VM6; }   // retires all 8 loads of tile t+1 (FIFO oldest-8 of 14)
        else if (s1) { VM0; }   // tail: drain so tile NT-1 is fully landed
        SBAR;
    }

    // epilogue: segmented bf16 store (q|k|v each [M][2048])
    #pragma unroll
    for (int mf = 0; mf < 8; ++mf)
        #pragma unroll
        for (int nf = 0; nf < 4; ++nf) {
            int col = n0 + wc * 64 + nf * 16 + l16;
            size_t base = ((size_t)(col >> 11) * M) * 2048 + (col & 2047);
            #pragma unroll
            for (int r = 0; r < 4; ++r) {
                int row = m0 + wr * 128 + mf * 16 + quad * 4 + r;
                Cv[base + (size_t)row * 2048] = f2bf(acc[mf][nf][r]);
            }
        }
}

// ---------------- GEMM: C[M][N] = A[M][K] * Bt[N][K]^T  (bf16 in, fp32 acc) ----------------
// 128^2 tile, register-staged, XOR-swizzled LDS. Kept for the output projection.
template<int FP32OUT>
__global__ __launch_bounds__(256, 2) void gemm_bt_k(
    const u16* __restrict__ A, const u16* __restrict__ Bt, void* __restrict__ Cv,
    int M, int N, int K)
{
    __shared__ u16 As[128 * 64];
    __shared__ u16 Bs[128 * 64];
    const int tid = threadIdx.x, wave = tid >> 6, lane = tid & 63;
    const int quad = lane >> 4, l16 = lane & 15;
    const int m0 = blockIdx.y * 128, n0 = blockIdx.x * 128;
    const int mw = (wave & 1) * 64, nw = (wave >> 1) * 64;

    f32x4 zero = {0.f, 0.f, 0.f, 0.f};
    f32x4 acc[4][4];
    #pragma unroll
    for (int i = 0; i < 4; i++)
        #pragma unroll
        for (int j = 0; j < 4; j++) acc[i][j] = zero;

    const int sr = tid >> 3;          // 0..31
    const int sj = tid & 7;           // k-chunk
    const u16* ga0 = A  + (size_t)(m0 + sr) * K + sj * 8;
    const u16* gb0 = Bt + (size_t)(n0 + sr) * K + sj * 8;
    int woff[4];
    #pragma unroll
    for (int it = 0; it < 4; ++it) {
        int r = it * 32 + sr;
        woff[it] = r * 64 + ((sj ^ (r & 7)) * 8);
    }

    short8 abuf[4], bbuf[4];
    #pragma unroll
    for (int it = 0; it < 4; ++it) {
        abuf[it] = *(const short8*)(ga0 + (size_t)(it * 32) * K);
        bbuf[it] = *(const short8*)(gb0 + (size_t)(it * 32) * K);
    }
    #pragma unroll
    for (int it = 0; it < 4; ++it) {
        *(short8*)&As[woff[it]] = abuf[it];
        *(short8*)&Bs[woff[it]] = bbuf[it];
    }
    __syncthreads();

    const int rsw = l16 & 7;

    for (int kk = 0; kk < K; kk += 64) {
        const bool pre = (kk + 64 < K);
        if (pre) {
            #pragma unroll
            for (int it = 0; it < 4; ++it) {
                abuf[it] = *(const short8*)(ga0 + (size_t)(it * 32) * K + (kk + 64));
                bbuf[it] = *(const short8*)(gb0 + (size_t)(it * 32) * K + (kk + 64));
            }
        }
        #pragma unroll
        for (int ks = 0; ks < 2; ks++) {
            const int ch = ((ks * 4 + quad) ^ rsw) * 8;
            short8 af[4], bfr[4];
            #pragma unroll
            for (int mf = 0; mf < 4; mf++)
                af[mf] = *(const short8*)&As[(mw + mf * 16 + l16) * 64 + ch];
            #pragma unroll
            for (int nf = 0; nf < 4; nf++)
                bfr[nf] = *(const short8*)&Bs[(nw + nf * 16 + l16) * 64 + ch];
            #pragma unroll
            for (int mf = 0; mf < 4; mf++)
                #pragma unroll
                for (int nf = 0; nf < 4; nf++)
                    acc[mf][nf] = __builtin_amdgcn_mfma_f32_16x16x32_bf16(af[mf], bfr[nf], acc[mf][nf], 0, 0, 0);
        }
        if (pre) {
            __syncthreads();
            #pragma unroll
            for (int it = 0; it < 4; ++it) {
                *(short8*)&As[woff[it]] = abuf[it];
                *(short8*)&Bs[woff[it]] = bbuf[it];
            }
            __syncthreads();
        }
    }

    #pragma unroll
    for (int mf = 0; mf < 4; mf++)
        #pragma unroll
        for (int nf = 0; nf < 4; nf++)
            #pragma unroll
            for (int r = 0; r < 4; r++) {
                int row = m0 + mw + mf * 16 + quad * 4 + r;
                int col = n0 + nw + nf * 16 + l16;
                if (FP32OUT) ((float*)Cv)[(size_t)row * N + col] = acc[mf][nf][r];
                else         ((u16*) Cv)[(size_t)row * N + col] = f2bf(acc[mf][nf][r]);
            }
}

// ---------------- Flash attention, causal, paired complementary 64-row subtiles ----------------
__global__ __launch_bounds__(256, 2) void attn_k(
    const u16* __restrict__ q, const u16* __restrict__ k,
    const u16* __restrict__ vt, u16* __restrict__ o)
{
    __shared__ __align__(16) u16 Ks[64 * 132];   // [key][d], pad 4
    __shared__ __align__(16) u16 Vs[128 * 68];   // [d][key], pad 4 (= V^T)
    __shared__ __align__(16) u16 Pt[128 * 68];   // [qrow_local][key], pad 4
    const int tid = threadIdx.x, wave = tid >> 6, lane = tid & 63;
    const int quad = lane >> 4, l16 = lane & 15;
    const int h = blockIdx.y, b = blockIdx.z;
    const int p = (b & 1) ? (15 - (int)blockIdx.x) : (int)blockIdx.x;
    const int sub0 = p, sub1 = 31 - p;
    const int nkt = 32 - p;

    const int krow = tid >> 4, kc8 = tid & 15;
    const int vd   = tid >> 3, vc8 = tid & 7;
    const u16* kgp = k  + ((size_t)(b * AT_T) * AT_H + h) * 128;
    const u16* vgp = vt + ((size_t)(b * AT_H + h) * 128) * (size_t)AT_T;

    short8 qf[2][4];
    #pragma unroll
    for (int mf = 0; mf < 2; mf++) {
        int row = (mf ? sub1 : sub0) * 64 + wave * 16 + l16;
        const u16* qp = q + ((size_t)(b * AT_T + row) * AT_H + h) * 128 + quad * 8;
        #pragma unroll
        for (int ks = 0; ks < 4; ks++)
            qf[mf][ks] = *(const short8*)(qp + ks * 32);
    }

    f32x4 zero = {0.f, 0.f, 0.f, 0.f};
    f32x4 Oacc[2][8];
    #pragma unroll
    for (int i = 0; i < 2; i++)
        #pragma unroll
        for (int j = 0; j < 8; j++) Oacc[i][j] = zero;
    float l_i[2] = {0.f, 0.f};

    short8 kreg[4], vreg[4];
    #pragma unroll
    for (int it = 0; it < 4; ++it) {
        kreg[it] = *(const short8*)(kgp + (size_t)(krow + it * 16) * 2048 + kc8 * 8);
        vreg[it] = *(const short8*)(vgp + (size_t)(vd + it * 32) * AT_T + vc8 * 8);
    }
    #pragma unroll
    for (int it = 0; it < 4; ++it) {
        *(short8*)&Ks[(krow + it * 16) * 132 + kc8 * 8] = kreg[it];
        *(short8*)&Vs[(vd + it * 32) * 68 + vc8 * 8] = vreg[it];
    }
    __syncthreads();

    for (int kt = 0; kt < nkt; ++kt) {
        const bool pre = (kt + 1 < nkt);
        if (pre) {
            #pragma unroll
            for (int it = 0; it < 4; ++it) {
                kreg[it] = *(const short8*)(kgp + (size_t)((kt + 1) * 64 + krow + it * 16) * 2048 + kc8 * 8);
                vreg[it] = *(const short8*)(vgp + (size_t)(vd + it * 32) * AT_T + (kt + 1) * 64 + vc8 * 8);
            }
        }
        const bool actA = (kt <= sub0);

        f32x4 St[4][2];
        #pragma unroll
        for (int mt = 0; mt < 4; mt++) { St[mt][0] = zero; St[mt][1] = zero; }
        #pragma unroll
        for (int mt = 0; mt < 4; mt++) {
            short8 af[4];
            #pragma unroll
            for (int ks = 0; ks < 4; ks++)
                af[ks] = *(const short8*)&Ks[(mt * 16 + l16) * 132 + ks * 32 + quad * 8];
            #pragma unroll
            for (int ks = 0; ks < 4; ks++)
                St[mt][1] = __builtin_amdgcn_mfma_f32_16x16x32_bf16(af[ks], qf[1][ks], St[mt][1], 0, 0, 0);
            if (actA) {
                #pragma unroll
                for (int ks = 0; ks < 4; ks++)
                    St[mt][0] = __builtin_amdgcn_mfma_f32_16x16x32_bf16(af[ks], qf[0][ks], St[mt][0], 0, 0, 0);
            }
        }

        #pragma unroll
        for (int mf = 0; mf < 2; mf++) {
            if (mf == 0 && !actA) continue;
            const int sub = mf ? sub1 : sub0;
            if (kt == sub) {
                int qrow = sub * 64 + wave * 16 + l16;
                #pragma unroll
                for (int mt = 0; mt < 4; mt++)
                    #pragma unroll
                    for (int r = 0; r < 4; r++) {
                        int key = kt * 64 + mt * 16 + quad * 4 + r;
                        if (key > qrow) St[mt][mf][r] = -1e30f;
                    }
            }
            float rs = 0.f;
            #pragma unroll
            for (int mt = 0; mt < 4; mt++)
                #pragma unroll
                for (int r = 0; r < 4; r++) {
                    float pv = __expf(St[mt][mf][r]);
                    St[mt][mf][r] = pv;
                    rs += pv;
                }
            rs += __shfl_xor(rs, 16, 64);
            rs += __shfl_xor(rs, 32, 64);
            l_i[mf] += rs;
            u16* pp = &Pt[(mf * 64 + wave * 16 + l16) * 68 + quad * 4];
            #pragma unroll
            for (int mt = 0; mt < 4; mt++) {
                *(unsigned*)(pp + mt * 16)     = pack_bf2(St[mt][mf][0], St[mt][mf][1]);
                *(unsigned*)(pp + mt * 16 + 2) = pack_bf2(St[mt][mf][2], St[mt][mf][3]);
            }
        }

        short8 pf[2][2];
        #pragma unroll
        for (int mf = 0; mf < 2; mf++)
            #pragma unroll
            for (int ks = 0; ks < 2; ks++)
                pf[mf][ks] = *(const short8*)&Pt[(mf * 64 + wave * 16 + l16) * 68 + ks * 32 + quad * 8];

        #pragma unroll
        for (int mt = 0; mt < 8; mt++) {
            short8 vf[2];
            #pragma unroll
            for (int ks = 0; ks < 2; ks++)
                vf[ks] = *(const short8*)&Vs[(mt * 16 + l16) * 68 + ks * 32 + quad * 8];
            #pragma unroll
            for (int ks = 0; ks < 2; ks++) {
                Oacc[1][mt] = __builtin_amdgcn_mfma_f32_16x16x32_bf16(vf[ks], pf[1][ks], Oacc[1][mt], 0, 0, 0);
                if (actA)
                    Oacc[0][mt] = __builtin_amdgcn_mfma_f32_16x16x32_bf16(vf[ks], pf[0][ks], Oacc[0][mt], 0, 0, 0);
            }
        }

        __syncthreads();
        if (pre) {
            #pragma unroll
            for (int it = 0; it < 4; ++it) {
                *(short8*)&Ks[(krow + it * 16) * 132 + kc8 * 8] = kreg[it];
                *(short8*)&Vs[(vd + it * 32) * 68 + vc8 * 8] = vreg[it];
            }
        }
        __syncthreads();
    }

    #pragma unroll
    for (int mf = 0; mf < 2; mf++) {
        float inv = 1.0f / l_i[mf];
        int row = (mf ? sub1 : sub0) * 64 + wave * 16 + l16;
        u16* op = o + ((size_t)(b * AT_T + row) * AT_H + h) * 128 + quad * 4;
        #pragma unroll
        for (int mt = 0; mt < 8; mt++) {
            *(unsigned*)(op + mt * 16)     = pack_bf2(Oacc[mf][mt][0] * inv, Oacc[mf][mt][1] * inv);
            *(unsigned*)(op + mt * 16 + 2) = pack_bf2(Oacc[mf][mt][2] * inv, Oacc[mf][mt][3] * inv);
        }
    }
}

// ---------------- launch ----------------
extern "C" void kernel_launch(void* const* d_in, const int* in_sizes, int n_in,
                              void* d_out, int out_size, void* d_ws, size_t ws_size,
                              hipStream_t stream) {
    const float* x    = (const float*)d_in[0];
    const float* w_aq = (const float*)d_in[1];
    const float* w_ak = (const float*)d_in[2];
    const float* w_av = (const float*)d_in[3];
    const float* w_ao = (const float*)d_in[4];
    float* outp = (float*)d_out;

    u16* ws   = (u16*)d_ws;
    u16* xb   = ws;                           // [4096][2048]      x, bf16
    u16* wqb  = xb   + (size_t)NROW * HD;     // [6144 n][2048 k]  (wq|wk|wv transposed)
    u16* waob = wqb  + (size_t)3 * HD * AT_M; // [2048 m][2048 hd] (w_ao^T)
    u16* qb   = waob + (size_t)HD * AT_M;     // [B,T,H,D] (then kb, vb contiguous)
    u16* kb   = qb   + (size_t)NROW * HD;
    u16* vb   = kb   + (size_t)NROW * HD;
    u16* vtb  = vb   + (size_t)NROW * HD;     // [B,H,D,T]
    u16* ob   = xb;                           // alias: xb dead after projections

    // 1) casts / transposes
    cast_bf16_k<<<(NROW * HD / 4 + 255) / 256, 256, 0, stream>>>(x, xb, NROW * HD / 4);
    dim3 tb(32, 8);
    tcast3_k<<<dim3(AT_D / 32, AT_M / 32, 48), tb, 0, stream>>>(w_aq, w_ak, w_av, wqb);
    tcast_k<<<dim3(AT_M / 32, HD / 32), tb, 0, stream>>>(w_ao, waob, HD, AT_M);

    // 2) fused QKV projection: 256^2 8-phase v2, grid 24x16 = 384 blocks
    gemm256_8ph_k<<<dim3(3 * HD / 256, NROW / 256), 512, 0, stream>>>(xb, wqb, qb, NROW, 3 * HD, AT_M);

    // 3) RoPE on q,k (q scaled by 1/128)
    rope_k<<<(NROW * AT_H * 64 + 255) / 256, 256, 0, stream>>>(qb, kb, NROW * AT_H * 64);

    // 4) v -> [B,H,D,T]
    tbf16_k<<<dim3(HD / 32, AT_T / 32, AT_B), tb, 0, stream>>>(vb, vtb, AT_T, HD);

    // 5) attention (paired complementary subtiles, prefetch, max-free softmax)
    attn_k<<<dim3(16, AT_H, AT_B), 256, 0, stream>>>(qb, kb, vtb, ob);

    // 6) output projection (fp32 out)
    gemm_bt_k<1><<<dim3(AT_M / 128, NROW / 128), 256, 0, stream>>>(ob, waob, outp, NROW, AT_M, HD);
}

// Round 6
// 379.945 us; speedup vs baseline: 1.0845x; 1.0577x over previous
//
#include <hip/hip_runtime.h>
#include <hip/hip_bf16.h>
#include <cmath>

typedef unsigned short u16;
typedef __attribute__((ext_vector_type(8))) short short8;
typedef __attribute__((ext_vector_type(4))) float f32x4;
typedef __attribute__((ext_vector_type(4))) unsigned short u16x4;

#define AT_B 2
#define AT_T 2048
#define AT_H 16
#define AT_D 128
#define AT_M 2048
#define NROW (AT_B*AT_T)   // 4096
#define HD   (AT_H*AT_D)   // 2048

__device__ __forceinline__ u16 f2bf(float f) {
    union { float f; unsigned u; } v; v.f = f;
    unsigned u = v.u;
    unsigned r = u + 0x7fffu + ((u >> 16) & 1u);
    return (u16)(r >> 16);
}
__device__ __forceinline__ float bf2f(u16 h) {
    union { unsigned u; float f; } v; v.u = ((unsigned)h) << 16;
    return v.f;
}
__device__ __forceinline__ unsigned pack_bf2(float a, float b) {
    __hip_bfloat162 t = __float22bfloat162_rn(make_float2(a, b));
    union { __hip_bfloat162 h; unsigned u; } v; v.h = t;
    return v.u;
}

// async global->LDS DMA, 16B per lane. LDS dest = wave-uniform base + lane*16.
__device__ __forceinline__ void gload16(const u16* g, u16* l) {
    __builtin_amdgcn_global_load_lds(
        (const __attribute__((address_space(1))) void*)g,
        (__attribute__((address_space(3))) void*)l, 16, 0, 0);
}

// LDS chunk-XOR swizzle (involution): 16-B chunks, chunk ^= row&7.
// Keeps every b128 access 16-B aligned; <=2-way bank aliasing on r/w (free).
__device__ __forceinline__ int swz128(int row, int pos) {   // row stride 128 u16
    return row * 128 + ((((pos >> 3) ^ (row & 7)) << 3) | (pos & 7));
}
__device__ __forceinline__ int swz64(int row, int pos) {    // row stride 64 u16
    return row * 64 + ((((pos >> 3) ^ (row & 7)) << 3) | (pos & 7));
}

// ---------------- elementwise cast fp32 -> bf16 (vec4) ----------------
__global__ void cast_bf16_k(const float* __restrict__ in, u16* __restrict__ out, int n4) {
    int i = blockIdx.x * 256 + threadIdx.x;
    if (i >= n4) return;
    float4 v = ((const float4*)in)[i];
    u16x4 o;
    o.x = f2bf(v.x); o.y = f2bf(v.y); o.z = f2bf(v.z); o.w = f2bf(v.w);
    ((u16x4*)out)[i] = o;
}

// ------------- QKV weight transpose-cast: 3 weights in one launch -------------
__global__ void tcast3_k(const float* __restrict__ wq, const float* __restrict__ wk,
                         const float* __restrict__ wv, u16* __restrict__ out) {
    __shared__ float tile[32][33];
    int bx = blockIdx.x, by = blockIdx.y, bz = blockIdx.z;
    int which = bz >> 4, h = bz & 15;
    const float* ip = (which == 0 ? wq : which == 1 ? wk : wv) + (size_t)h * AT_M * AT_D;
    u16* op = out + ((size_t)which * AT_H + h) * AT_M * AT_D;
    int tx = threadIdx.x, ty = threadIdx.y;
    #pragma unroll
    for (int j = 0; j < 32; j += 8)
        tile[ty + j][tx] = ip[(size_t)(by * 32 + ty + j) * AT_D + bx * 32 + tx];
    __syncthreads();
    #pragma unroll
    for (int j = 0; j < 32; j += 8)
        op[(size_t)(bx * 32 + ty + j) * AT_M + by * 32 + tx] = f2bf(tile[tx][ty + j]);
}

// ------------- transpose-cast: in[R][C] fp32 -> out[C][R] bf16 (w_ao) -------------
__global__ void tcast_k(const float* __restrict__ in, u16* __restrict__ out, int R, int C) {
    __shared__ float tile[32][33];
    int bx = blockIdx.x, by = blockIdx.y;
    int tx = threadIdx.x, ty = threadIdx.y;
    #pragma unroll
    for (int j = 0; j < 32; j += 8)
        tile[ty + j][tx] = in[(size_t)(by * 32 + ty + j) * C + bx * 32 + tx];
    __syncthreads();
    #pragma unroll
    for (int j = 0; j < 32; j += 8)
        out[(size_t)(bx * 32 + ty + j) * R + by * 32 + tx] = f2bf(tile[tx][ty + j]);
}

// ------------- batched transpose bf16 -> bf16: in[bz][R][C] -> out[bz][C][R] -------------
__global__ void tbf16_k(const u16* __restrict__ in, u16* __restrict__ out, int R, int C) {
    __shared__ u16 tile[32][33];
    int bx = blockIdx.x, by = blockIdx.y, bz = blockIdx.z;
    const u16* ip = in + (size_t)bz * R * C;
    u16* op = out + (size_t)bz * R * C;
    int tx = threadIdx.x, ty = threadIdx.y;
    #pragma unroll
    for (int j = 0; j < 32; j += 8)
        tile[ty + j][tx] = ip[(size_t)(by * 32 + ty + j) * C + bx * 32 + tx];
    __syncthreads();
    #pragma unroll
    for (int j = 0; j < 32; j += 8)
        op[(size_t)(bx * 32 + ty + j) * R + by * 32 + tx] = tile[tx][ty + j];
}

// ---------------- RoPE in place; q additionally scaled by 1/128 (muP) ----------------
__global__ void rope_k(u16* __restrict__ q, u16* __restrict__ k, int total) {
    int i = blockIdx.x * 256 + threadIdx.x;
    if (i >= total) return;
    int d = i & 63;
    int rest = i >> 6;                 // (b*T+t)*H + h
    int t = (rest >> 4) & (AT_T - 1);
    size_t base = (size_t)rest * 128;
    float freq = __expf(-(float)d * (9.210340371976184f / 64.0f)); // 10000^{-d/64}
    float ang = (float)t * freq;
    float s, c;
    sincosf(ang, &s, &c);
    const float qs = 0.0078125f;  // 1/128, exact
    float qe = bf2f(q[base + d]), qo = bf2f(q[base + d + 64]);
    q[base + d]      = f2bf((qe * c - qo * s) * qs);
    q[base + d + 64] = f2bf((qe * s + qo * c) * qs);
    float ke = bf2f(k[base + d]), ko = bf2f(k[base + d + 64]);
    k[base + d]      = f2bf(ke * c - ko * s);
    k[base + d + 64] = f2bf(ke * s + ko * c);
}

// =================================================================================
// 256x192-tile QKV GEMM (proven R3 structure, 117.6 us / 876 TF), 512 threads.
// global_load_lds staging, involution chunk swizzle, dbuf LDS, counted vmcnt(7).
// =================================================================================
#define G_ASZ (256*64)
#define G_BSZ (192*64)
#define G_STRIDE (G_ASZ + G_BSZ)
__global__ __launch_bounds__(512, 2) void gemm256_qkv_k(
    const u16* __restrict__ A, const u16* __restrict__ Bt, u16* __restrict__ Cv,
    int M, int N, int K)
{
    __shared__ __align__(1024) u16 smem[2 * G_STRIDE];   // 112 KiB
    const int tid  = threadIdx.x;
    const int wave = tid >> 6, lane = tid & 63;
    const int quad = lane >> 4, l16 = lane & 15;
    const int wr = wave >> 2, wc = wave & 3;
    const int m0 = blockIdx.y * 256, n0 = blockIdx.x * 192;

    const int rl = lane >> 3;               // 0..7
    const int jc = (lane & 7) ^ rl;         // pre-swizzled source k-chunk
    const u16* ga = A  + (size_t)(m0 + wave * 8 + rl) * K + jc * 8;
    const u16* gb = Bt + (size_t)(n0 + wave * 8 + rl) * K + jc * 8;
    const int ldst = (wave * 64) * 8;

    f32x4 zero = {0.f, 0.f, 0.f, 0.f};
    f32x4 acc[8][3];
    #pragma unroll
    for (int i = 0; i < 8; i++)
        #pragma unroll
        for (int j = 0; j < 3; j++) acc[i][j] = zero;

    const int NT = K >> 6;

    {
        #pragma unroll
        for (int i = 0; i < 4; ++i) gload16(ga + (size_t)(i * 64) * K,      smem + i * 512 * 8 + ldst);
        #pragma unroll
        for (int i = 0; i < 3; ++i) gload16(gb + (size_t)(i * 64) * K,      smem + G_ASZ + i * 512 * 8 + ldst);
        #pragma unroll
        for (int i = 0; i < 4; ++i) gload16(ga + (size_t)(i * 64) * K + 64, smem + G_STRIDE + i * 512 * 8 + ldst);
        #pragma unroll
        for (int i = 0; i < 3; ++i) gload16(gb + (size_t)(i * 64) * K + 64, smem + G_STRIDE + G_ASZ + i * 512 * 8 + ldst);
    }
    asm volatile("s_waitcnt vmcnt(7)" ::: "memory");
    __builtin_amdgcn_s_barrier();
    asm volatile("" ::: "memory");

    const int arow = (wr * 128 + l16) * 64;
    const int brow = (wc * 48  + l16) * 64;
    const int rsw  = l16 & 7;

    for (int t = 0; t < NT; ++t) {
        const int boff = (t & 1) * G_STRIDE;
        const u16* as = smem + boff;
        const u16* bs = smem + boff + G_ASZ;
        #pragma unroll
        for (int ks = 0; ks < 2; ++ks) {
            const int ch = ((ks * 4 + quad) ^ rsw) * 8;
            short8 af[8], bfr[3];
            #pragma unroll
            for (int mf = 0; mf < 8; ++mf)
                af[mf] = *(const short8*)&as[arow + mf * (16 * 64) + ch];
            #pragma unroll
            for (int nf = 0; nf < 3; ++nf)
                bfr[nf] = *(const short8*)&bs[brow + nf * (16 * 64) + ch];
            #pragma unroll
            for (int mf = 0; mf < 8; ++mf)
                #pragma unroll
                for (int nf = 0; nf < 3; ++nf)
                    acc[mf][nf] = __builtin_amdgcn_mfma_f32_16x16x32_bf16(af[mf], bfr[nf], acc[mf][nf], 0, 0, 0);
        }
        if (t + 1 < NT) {
            asm volatile("s_waitcnt lgkmcnt(0)" ::: "memory");
            __builtin_amdgcn_s_barrier();
            asm volatile("" ::: "memory");
            if (t + 2 < NT) {
                const int kk = (t + 2) * 64;
                u16* asw = smem + boff;
                u16* bsw = smem + boff + G_ASZ;
                #pragma unroll
                for (int i = 0; i < 4; ++i)
                    gload16(ga + (size_t)(i * 64) * K + kk, asw + i * 512 * 8 + ldst);
                #pragma unroll
                for (int i = 0; i < 3; ++i)
                    gload16(gb + (size_t)(i * 64) * K + kk, bsw + i * 512 * 8 + ldst);
                asm volatile("s_waitcnt vmcnt(7)" ::: "memory");
            } else {
                asm volatile("s_waitcnt vmcnt(0)" ::: "memory");
            }
            __builtin_amdgcn_s_barrier();
            asm volatile("" ::: "memory");
        }
    }

    #pragma unroll
    for (int mf = 0; mf < 8; ++mf)
        #pragma unroll
        for (int nf = 0; nf < 3; ++nf) {
            int col = n0 + wc * 48 + nf * 16 + l16;
            size_t base = ((size_t)(col >> 11) * M) * 2048 + (col & 2047);
            #pragma unroll
            for (int r = 0; r < 4; ++r) {
                int row = m0 + wr * 128 + mf * 16 + quad * 4 + r;
                Cv[base + (size_t)row * 2048] = f2bf(acc[mf][nf][r]);
            }
        }
}

// ---------------- GEMM: C[M][N] = A[M][K] * Bt[N][K]^T  (bf16 in, fp32 acc) ----------------
template<int FP32OUT>
__global__ __launch_bounds__(256, 2) void gemm_bt_k(
    const u16* __restrict__ A, const u16* __restrict__ Bt, void* __restrict__ Cv,
    int M, int N, int K)
{
    __shared__ u16 As[128 * 64];
    __shared__ u16 Bs[128 * 64];
    const int tid = threadIdx.x, wave = tid >> 6, lane = tid & 63;
    const int quad = lane >> 4, l16 = lane & 15;
    const int m0 = blockIdx.y * 128, n0 = blockIdx.x * 128;
    const int mw = (wave & 1) * 64, nw = (wave >> 1) * 64;

    f32x4 zero = {0.f, 0.f, 0.f, 0.f};
    f32x4 acc[4][4];
    #pragma unroll
    for (int i = 0; i < 4; i++)
        #pragma unroll
        for (int j = 0; j < 4; j++) acc[i][j] = zero;

    const int sr = tid >> 3;          // 0..31
    const int sj = tid & 7;           // k-chunk
    const u16* ga0 = A  + (size_t)(m0 + sr) * K + sj * 8;
    const u16* gb0 = Bt + (size_t)(n0 + sr) * K + sj * 8;
    int woff[4];
    #pragma unroll
    for (int it = 0; it < 4; ++it) {
        int r = it * 32 + sr;
        woff[it] = r * 64 + ((sj ^ (r & 7)) * 8);
    }

    short8 abuf[4], bbuf[4];
    #pragma unroll
    for (int it = 0; it < 4; ++it) {
        abuf[it] = *(const short8*)(ga0 + (size_t)(it * 32) * K);
        bbuf[it] = *(const short8*)(gb0 + (size_t)(it * 32) * K);
    }
    #pragma unroll
    for (int it = 0; it < 4; ++it) {
        *(short8*)&As[woff[it]] = abuf[it];
        *(short8*)&Bs[woff[it]] = bbuf[it];
    }
    __syncthreads();

    const int rsw = l16 & 7;

    for (int kk = 0; kk < K; kk += 64) {
        const bool pre = (kk + 64 < K);
        if (pre) {
            #pragma unroll
            for (int it = 0; it < 4; ++it) {
                abuf[it] = *(const short8*)(ga0 + (size_t)(it * 32) * K + (kk + 64));
                bbuf[it] = *(const short8*)(gb0 + (size_t)(it * 32) * K + (kk + 64));
            }
        }
        #pragma unroll
        for (int ks = 0; ks < 2; ks++) {
            const int ch = ((ks * 4 + quad) ^ rsw) * 8;
            short8 af[4], bfr[4];
            #pragma unroll
            for (int mf = 0; mf < 4; mf++)
                af[mf] = *(const short8*)&As[(mw + mf * 16 + l16) * 64 + ch];
            #pragma unroll
            for (int nf = 0; nf < 4; nf++)
                bfr[nf] = *(const short8*)&Bs[(nw + nf * 16 + l16) * 64 + ch];
            #pragma unroll
            for (int mf = 0; mf < 4; mf++)
                #pragma unroll
                for (int nf = 0; nf < 4; nf++)
                    acc[mf][nf] = __builtin_amdgcn_mfma_f32_16x16x32_bf16(af[mf], bfr[nf], acc[mf][nf], 0, 0, 0);
        }
        if (pre) {
            __syncthreads();
            #pragma unroll
            for (int it = 0; it < 4; ++it) {
                *(short8*)&As[woff[it]] = abuf[it];
                *(short8*)&Bs[woff[it]] = bbuf[it];
            }
            __syncthreads();
        }
    }

    #pragma unroll
    for (int mf = 0; mf < 4; mf++)
        #pragma unroll
        for (int nf = 0; nf < 4; nf++)
            #pragma unroll
            for (int r = 0; r < 4; r++) {
                int row = m0 + mw + mf * 16 + quad * 4 + r;
                int col = n0 + nw + nf * 16 + l16;
                if (FP32OUT) ((float*)Cv)[(size_t)row * N + col] = acc[mf][nf][r];
                else         ((u16*) Cv)[(size_t)row * N + col] = f2bf(acc[mf][nf][r]);
            }
}

// ---------------- Flash attention, causal, paired complementary 64-row subtiles ----------------
// LDS: power-of-2 row strides + chunk-XOR swizzle (16-B-aligned b128, <=2-way banks).
__global__ __launch_bounds__(256, 2) void attn_k(
    const u16* __restrict__ q, const u16* __restrict__ k,
    const u16* __restrict__ vt, u16* __restrict__ o)
{
    __shared__ __align__(1024) u16 Ks[64 * 128];   // [key][d], swizzled
    __shared__ __align__(1024) u16 Vs[128 * 64];   // [d][key], swizzled (= V^T)
    __shared__ __align__(1024) u16 Pt[128 * 64];   // [qrow_local][key], swizzled
    const int tid = threadIdx.x, wave = tid >> 6, lane = tid & 63;
    const int quad = lane >> 4, l16 = lane & 15;
    const int h = blockIdx.y, b = blockIdx.z;
    const int p = (b & 1) ? (15 - (int)blockIdx.x) : (int)blockIdx.x;
    const int sub0 = p, sub1 = 31 - p;
    const int nkt = 32 - p;

    const int krow = tid >> 4, kc8 = tid & 15;
    const int vd   = tid >> 3, vc8 = tid & 7;
    const u16* kgp = k  + ((size_t)(b * AT_T) * AT_H + h) * 128;
    const u16* vgp = vt + ((size_t)(b * AT_H + h) * 128) * (size_t)AT_T;

    short8 qf[2][4];
    #pragma unroll
    for (int mf = 0; mf < 2; mf++) {
        int row = (mf ? sub1 : sub0) * 64 + wave * 16 + l16;
        const u16* qp = q + ((size_t)(b * AT_T + row) * AT_H + h) * 128 + quad * 8;
        #pragma unroll
        for (int ks = 0; ks < 4; ks++)
            qf[mf][ks] = *(const short8*)(qp + ks * 32);
    }

    f32x4 zero = {0.f, 0.f, 0.f, 0.f};
    f32x4 Oacc[2][8];
    #pragma unroll
    for (int i = 0; i < 2; i++)
        #pragma unroll
        for (int j = 0; j < 8; j++) Oacc[i][j] = zero;
    float l_i[2] = {0.f, 0.f};

    short8 kreg[4], vreg[4];
    #pragma unroll
    for (int it = 0; it < 4; ++it) {
        kreg[it] = *(const short8*)(kgp + (size_t)(krow + it * 16) * 2048 + kc8 * 8);
        vreg[it] = *(const short8*)(vgp + (size_t)(vd + it * 32) * AT_T + vc8 * 8);
    }
    #pragma unroll
    for (int it = 0; it < 4; ++it) {
        *(short8*)&Ks[swz128(krow + it * 16, kc8 * 8)] = kreg[it];
        *(short8*)&Vs[swz64(vd + it * 32, vc8 * 8)] = vreg[it];
    }
    __syncthreads();

    for (int kt = 0; kt < nkt; ++kt) {
        const bool pre = (kt + 1 < nkt);
        if (pre) {
            #pragma unroll
            for (int it = 0; it < 4; ++it) {
                kreg[it] = *(const short8*)(kgp + (size_t)((kt + 1) * 64 + krow + it * 16) * 2048 + kc8 * 8);
                vreg[it] = *(const short8*)(vgp + (size_t)(vd + it * 32) * AT_T + (kt + 1) * 64 + vc8 * 8);
            }
        }
        const bool actA = (kt <= sub0);

        f32x4 St[4][2];
        #pragma unroll
        for (int mt = 0; mt < 4; mt++) { St[mt][0] = zero; St[mt][1] = zero; }
        #pragma unroll
        for (int mt = 0; mt < 4; mt++) {
            short8 af[4];
            #pragma unroll
            for (int ks = 0; ks < 4; ks++)
                af[ks] = *(const short8*)&Ks[swz128(mt * 16 + l16, ks * 32 + quad * 8)];
            #pragma unroll
            for (int ks = 0; ks < 4; ks++)
                St[mt][1] = __builtin_amdgcn_mfma_f32_16x16x32_bf16(af[ks], qf[1][ks], St[mt][1], 0, 0, 0);
            if (actA) {
                #pragma unroll
                for (int ks = 0; ks < 4; ks++)
                    St[mt][0] = __builtin_amdgcn_mfma_f32_16x16x32_bf16(af[ks], qf[0][ks], St[mt][0], 0, 0, 0);
            }
        }

        #pragma unroll
        for (int mf = 0; mf < 2; mf++) {
            if (mf == 0 && !actA) continue;
            const int sub = mf ? sub1 : sub0;
            if (kt == sub) {
                int qrow = sub * 64 + wave * 16 + l16;
                #pragma unroll
                for (int mt = 0; mt < 4; mt++)
                    #pragma unroll
                    for (int r = 0; r < 4; r++) {
                        int key = kt * 64 + mt * 16 + quad * 4 + r;
                        if (key > qrow) St[mt][mf][r] = -1e30f;
                    }
            }
            float rs = 0.f;
            #pragma unroll
            for (int mt = 0; mt < 4; mt++)
                #pragma unroll
                for (int r = 0; r < 4; r++) {
                    float pv = __expf(St[mt][mf][r]);
                    St[mt][mf][r] = pv;
                    rs += pv;
                }
            rs += __shfl_xor(rs, 16, 64);
            rs += __shfl_xor(rs, 32, 64);
            l_i[mf] += rs;
            const int prow = mf * 64 + wave * 16 + l16;
            #pragma unroll
            for (int mt = 0; mt < 4; mt++) {
                int sp = swz64(prow, mt * 16 + quad * 4);
                *(unsigned*)&Pt[sp]     = pack_bf2(St[mt][mf][0], St[mt][mf][1]);
                *(unsigned*)&Pt[sp + 2] = pack_bf2(St[mt][mf][2], St[mt][mf][3]);
            }
        }

        short8 pf[2][2];
        #pragma unroll
        for (int mf = 0; mf < 2; mf++)
            #pragma unroll
            for (int ks = 0; ks < 2; ks++)
                pf[mf][ks] = *(const short8*)&Pt[swz64(mf * 64 + wave * 16 + l16, ks * 32 + quad * 8)];

        #pragma unroll
        for (int mt = 0; mt < 8; mt++) {
            short8 vf[2];
            #pragma unroll
            for (int ks = 0; ks < 2; ks++)
                vf[ks] = *(const short8*)&Vs[swz64(mt * 16 + l16, ks * 32 + quad * 8)];
            #pragma unroll
            for (int ks = 0; ks < 2; ks++) {
                Oacc[1][mt] = __builtin_amdgcn_mfma_f32_16x16x32_bf16(vf[ks], pf[1][ks], Oacc[1][mt], 0, 0, 0);
                if (actA)
                    Oacc[0][mt] = __builtin_amdgcn_mfma_f32_16x16x32_bf16(vf[ks], pf[0][ks], Oacc[0][mt], 0, 0, 0);
            }
        }

        __syncthreads();
        if (pre) {
            #pragma unroll
            for (int it = 0; it < 4; ++it) {
                *(short8*)&Ks[swz128(krow + it * 16, kc8 * 8)] = kreg[it];
                *(short8*)&Vs[swz64(vd + it * 32, vc8 * 8)] = vreg[it];
            }
        }
        __syncthreads();
    }

    #pragma unroll
    for (int mf = 0; mf < 2; mf++) {
        float inv = 1.0f / l_i[mf];
        int row = (mf ? sub1 : sub0) * 64 + wave * 16 + l16;
        u16* op = o + ((size_t)(b * AT_T + row) * AT_H + h) * 128 + quad * 4;
        #pragma unroll
        for (int mt = 0; mt < 8; mt++) {
            *(unsigned*)(op + mt * 16)     = pack_bf2(Oacc[mf][mt][0] * inv, Oacc[mf][mt][1] * inv);
            *(unsigned*)(op + mt * 16 + 2) = pack_bf2(Oacc[mf][mt][2] * inv, Oacc[mf][mt][3] * inv);
        }
    }
}

// ---------------- launch ----------------
extern "C" void kernel_launch(void* const* d_in, const int* in_sizes, int n_in,
                              void* d_out, int out_size, void* d_ws, size_t ws_size,
                              hipStream_t stream) {
    const float* x    = (const float*)d_in[0];
    const float* w_aq = (const float*)d_in[1];
    const float* w_ak = (const float*)d_in[2];
    const float* w_av = (const float*)d_in[3];
    const float* w_ao = (const float*)d_in[4];
    float* outp = (float*)d_out;

    u16* ws   = (u16*)d_ws;
    u16* xb   = ws;                           // [4096][2048]      x, bf16
    u16* wqb  = xb   + (size_t)NROW * HD;     // [6144 n][2048 k]  (wq|wk|wv transposed)
    u16* waob = wqb  + (size_t)3 * HD * AT_M; // [2048 m][2048 hd] (w_ao^T)
    u16* qb   = waob + (size_t)HD * AT_M;     // [B,T,H,D] (then kb, vb contiguous)
    u16* kb   = qb   + (size_t)NROW * HD;
    u16* vb   = kb   + (size_t)NROW * HD;
    u16* vtb  = vb   + (size_t)NROW * HD;     // [B,H,D,T]
    u16* ob   = xb;                           // alias: xb dead after projections

    // 1) casts / transposes
    cast_bf16_k<<<(NROW * HD / 4 + 255) / 256, 256, 0, stream>>>(x, xb, NROW * HD / 4);
    dim3 tb(32, 8);
    tcast3_k<<<dim3(AT_D / 32, AT_M / 32, 48), tb, 0, stream>>>(w_aq, w_ak, w_av, wqb);
    tcast_k<<<dim3(AT_M / 32, HD / 32), tb, 0, stream>>>(w_ao, waob, HD, AT_M);

    // 2) fused QKV projection: 256x192 tile, grid 32x16 = 512 blocks (2 full CU rounds)
    gemm256_qkv_k<<<dim3(3 * HD / 192, NROW / 256), 512, 0, stream>>>(xb, wqb, qb, NROW, 3 * HD, AT_M);

    // 3) RoPE on q,k (q scaled by 1/128)
    rope_k<<<(NROW * AT_H * 64 + 255) / 256, 256, 0, stream>>>(qb, kb, NROW * AT_H * 64);

    // 4) v -> [B,H,D,T]
    tbf16_k<<<dim3(HD / 32, AT_T / 32, AT_B), tb, 0, stream>>>(vb, vtb, AT_T, HD);

    // 5) attention (paired complementary subtiles, prefetch, max-free softmax)
    attn_k<<<dim3(16, AT_H, AT_B), 256, 0, stream>>>(qb, kb, vtb, ob);

    // 6) output projection (fp32 out)
    gemm_bt_k<1><<<dim3(AT_M / 128, NROW / 128), 256, 0, stream>>>(ob, waob, outp, NROW, AT_M, HD);
}

// Round 8
// 368.300 us; speedup vs baseline: 1.1188x; 1.0316x over previous
//
#include <hip/hip_runtime.h>
#include <hip/hip_bf16.h>
#include <cmath>

typedef unsigned short u16;
typedef __attribute__((ext_vector_type(8))) short short8;
typedef __attribute__((ext_vector_type(4))) float f32x4;
typedef __attribute__((ext_vector_type(16))) float f32x16;
typedef __attribute__((ext_vector_type(4))) unsigned short u16x4;
typedef __attribute__((ext_vector_type(4))) unsigned int u32x4;

#define AT_B 2
#define AT_T 2048
#define AT_H 16
#define AT_D 128
#define AT_M 2048
#define NROW (AT_B*AT_T)   // 4096
#define HD   (AT_H*AT_D)   // 2048

__device__ __forceinline__ u16 f2bf(float f) {
    union { float f; unsigned u; } v; v.f = f;
    unsigned u = v.u;
    unsigned r = u + 0x7fffu + ((u >> 16) & 1u);
    return (u16)(r >> 16);
}
__device__ __forceinline__ float bf2f(u16 h) {
    union { unsigned u; float f; } v; v.u = ((unsigned)h) << 16;
    return v.f;
}
__device__ __forceinline__ unsigned pack_bf2(float a, float b) {
    __hip_bfloat162 t = __float22bfloat162_rn(make_float2(a, b));
    union { __hip_bfloat162 h; unsigned u; } v; v.h = t;
    return v.u;
}

// async global->LDS DMA, 16B per lane. LDS dest = wave-uniform base + lane*16.
__device__ __forceinline__ void gload16(const u16* g, u16* l) {
    __builtin_amdgcn_global_load_lds(
        (const __attribute__((address_space(1))) void*)g,
        (__attribute__((address_space(3))) void*)l, 16, 0, 0);
}

// ---------------- elementwise cast fp32 -> bf16 (vec4) ----------------
__global__ void cast_bf16_k(const float* __restrict__ in, u16* __restrict__ out, int n4) {
    int i = blockIdx.x * 256 + threadIdx.x;
    if (i >= n4) return;
    float4 v = ((const float4*)in)[i];
    u16x4 o;
    o.x = f2bf(v.x); o.y = f2bf(v.y); o.z = f2bf(v.z); o.w = f2bf(v.w);
    ((u16x4*)out)[i] = o;
}

// ------------- QKV weight transpose-cast: 3 weights in one launch -------------
__global__ void tcast3_k(const float* __restrict__ wq, const float* __restrict__ wk,
                         const float* __restrict__ wv, u16* __restrict__ out) {
    __shared__ float tile[32][33];
    int bx = blockIdx.x, by = blockIdx.y, bz = blockIdx.z;
    int which = bz >> 4, h = bz & 15;
    const float* ip = (which == 0 ? wq : which == 1 ? wk : wv) + (size_t)h * AT_M * AT_D;
    u16* op = out + ((size_t)which * AT_H + h) * AT_M * AT_D;
    int tx = threadIdx.x, ty = threadIdx.y;
    #pragma unroll
    for (int j = 0; j < 32; j += 8)
        tile[ty + j][tx] = ip[(size_t)(by * 32 + ty + j) * AT_D + bx * 32 + tx];
    __syncthreads();
    #pragma unroll
    for (int j = 0; j < 32; j += 8)
        op[(size_t)(bx * 32 + ty + j) * AT_M + by * 32 + tx] = f2bf(tile[tx][ty + j]);
}

// ------------- transpose-cast: in[R][C] fp32 -> out[C][R] bf16 (w_ao) -------------
__global__ void tcast_k(const float* __restrict__ in, u16* __restrict__ out, int R, int C) {
    __shared__ float tile[32][33];
    int bx = blockIdx.x, by = blockIdx.y;
    int tx = threadIdx.x, ty = threadIdx.y;
    #pragma unroll
    for (int j = 0; j < 32; j += 8)
        tile[ty + j][tx] = in[(size_t)(by * 32 + ty + j) * C + bx * 32 + tx];
    __syncthreads();
    #pragma unroll
    for (int j = 0; j < 32; j += 8)
        out[(size_t)(bx * 32 + ty + j) * R + by * 32 + tx] = f2bf(tile[tx][ty + j]);
}

// ------------- batched transpose bf16 -> bf16: in[bz][R][C] -> out[bz][C][R] -------------
__global__ void tbf16_k(const u16* __restrict__ in, u16* __restrict__ out, int R, int C) {
    __shared__ u16 tile[32][33];
    int bx = blockIdx.x, by = blockIdx.y, bz = blockIdx.z;
    const u16* ip = in + (size_t)bz * R * C;
    u16* op = out + (size_t)bz * R * C;
    int tx = threadIdx.x, ty = threadIdx.y;
    #pragma unroll
    for (int j = 0; j < 32; j += 8)
        tile[ty + j][tx] = ip[(size_t)(by * 32 + ty + j) * C + bx * 32 + tx];
    __syncthreads();
    #pragma unroll
    for (int j = 0; j < 32; j += 8)
        op[(size_t)(bx * 32 + ty + j) * R + by * 32 + tx] = tile[tx][ty + j];
}

// ---------------- RoPE in place; q additionally scaled by 1/128 (muP) ----------------
__global__ void rope_k(u16* __restrict__ q, u16* __restrict__ k, int total) {
    int i = blockIdx.x * 256 + threadIdx.x;
    if (i >= total) return;
    int d = i & 63;
    int rest = i >> 6;                 // (b*T+t)*H + h
    int t = (rest >> 4) & (AT_T - 1);
    size_t base = (size_t)rest * 128;
    float freq = __expf(-(float)d * (9.210340371976184f / 64.0f)); // 10000^{-d/64}
    float ang = (float)t * freq;
    float s, c;
    sincosf(ang, &s, &c);
    const float qs = 0.0078125f;  // 1/128, exact
    float qe = bf2f(q[base + d]), qo = bf2f(q[base + d + 64]);
    q[base + d]      = f2bf((qe * c - qo * s) * qs);
    q[base + d + 64] = f2bf((qe * s + qo * c) * qs);
    float ke = bf2f(k[base + d]), ko = bf2f(k[base + d + 64]);
    k[base + d]      = f2bf(ke * c - ko * s);
    k[base + d + 64] = f2bf(ke * s + ko * c);
}

// =================================================================================
// 256x192-tile QKV GEMM (proven R3 structure, 117.6 us / 876 TF), 512 threads.
// global_load_lds staging, involution chunk swizzle, dbuf LDS, counted vmcnt(7).
// =================================================================================
#define G_ASZ (256*64)
#define G_BSZ (192*64)
#define G_STRIDE (G_ASZ + G_BSZ)
__global__ __launch_bounds__(512, 2) void gemm256_qkv_k(
    const u16* __restrict__ A, const u16* __restrict__ Bt, u16* __restrict__ Cv,
    int M, int N, int K)
{
    __shared__ __align__(1024) u16 smem[2 * G_STRIDE];   // 112 KiB
    const int tid  = threadIdx.x;
    const int wave = tid >> 6, lane = tid & 63;
    const int quad = lane >> 4, l16 = lane & 15;
    const int wr = wave >> 2, wc = wave & 3;
    const int m0 = blockIdx.y * 256, n0 = blockIdx.x * 192;

    const int rl = lane >> 3;               // 0..7
    const int jc = (lane & 7) ^ rl;         // pre-swizzled source k-chunk
    const u16* ga = A  + (size_t)(m0 + wave * 8 + rl) * K + jc * 8;
    const u16* gb = Bt + (size_t)(n0 + wave * 8 + rl) * K + jc * 8;
    const int ldst = (wave * 64) * 8;

    f32x4 zero = {0.f, 0.f, 0.f, 0.f};
    f32x4 acc[8][3];
    #pragma unroll
    for (int i = 0; i < 8; i++)
        #pragma unroll
        for (int j = 0; j < 3; j++) acc[i][j] = zero;

    const int NT = K >> 6;

    {
        #pragma unroll
        for (int i = 0; i < 4; ++i) gload16(ga + (size_t)(i * 64) * K,      smem + i * 512 * 8 + ldst);
        #pragma unroll
        for (int i = 0; i < 3; ++i) gload16(gb + (size_t)(i * 64) * K,      smem + G_ASZ + i * 512 * 8 + ldst);
        #pragma unroll
        for (int i = 0; i < 4; ++i) gload16(ga + (size_t)(i * 64) * K + 64, smem + G_STRIDE + i * 512 * 8 + ldst);
        #pragma unroll
        for (int i = 0; i < 3; ++i) gload16(gb + (size_t)(i * 64) * K + 64, smem + G_STRIDE + G_ASZ + i * 512 * 8 + ldst);
    }
    asm volatile("s_waitcnt vmcnt(7)" ::: "memory");
    __builtin_amdgcn_s_barrier();
    asm volatile("" ::: "memory");

    const int arow = (wr * 128 + l16) * 64;
    const int brow = (wc * 48  + l16) * 64;
    const int rsw  = l16 & 7;

    for (int t = 0; t < NT; ++t) {
        const int boff = (t & 1) * G_STRIDE;
        const u16* as = smem + boff;
        const u16* bs = smem + boff + G_ASZ;
        #pragma unroll
        for (int ks = 0; ks < 2; ++ks) {
            const int ch = ((ks * 4 + quad) ^ rsw) * 8;
            short8 af[8], bfr[3];
            #pragma unroll
            for (int mf = 0; mf < 8; ++mf)
                af[mf] = *(const short8*)&as[arow + mf * (16 * 64) + ch];
            #pragma unroll
            for (int nf = 0; nf < 3; ++nf)
                bfr[nf] = *(const short8*)&bs[brow + nf * (16 * 64) + ch];
            #pragma unroll
            for (int mf = 0; mf < 8; ++mf)
                #pragma unroll
                for (int nf = 0; nf < 3; ++nf)
                    acc[mf][nf] = __builtin_amdgcn_mfma_f32_16x16x32_bf16(af[mf], bfr[nf], acc[mf][nf], 0, 0, 0);
        }
        if (t + 1 < NT) {
            asm volatile("s_waitcnt lgkmcnt(0)" ::: "memory");
            __builtin_amdgcn_s_barrier();
            asm volatile("" ::: "memory");
            if (t + 2 < NT) {
                const int kk = (t + 2) * 64;
                u16* asw = smem + boff;
                u16* bsw = smem + boff + G_ASZ;
                #pragma unroll
                for (int i = 0; i < 4; ++i)
                    gload16(ga + (size_t)(i * 64) * K + kk, asw + i * 512 * 8 + ldst);
                #pragma unroll
                for (int i = 0; i < 3; ++i)
                    gload16(gb + (size_t)(i * 64) * K + kk, bsw + i * 512 * 8 + ldst);
                asm volatile("s_waitcnt vmcnt(7)" ::: "memory");
            } else {
                asm volatile("s_waitcnt vmcnt(0)" ::: "memory");
            }
            __builtin_amdgcn_s_barrier();
            asm volatile("" ::: "memory");
        }
    }

    #pragma unroll
    for (int mf = 0; mf < 8; ++mf)
        #pragma unroll
        for (int nf = 0; nf < 3; ++nf) {
            int col = n0 + wc * 48 + nf * 16 + l16;
            size_t base = ((size_t)(col >> 11) * M) * 2048 + (col & 2047);
            #pragma unroll
            for (int r = 0; r < 4; ++r) {
                int row = m0 + wr * 128 + mf * 16 + quad * 4 + r;
                Cv[base + (size_t)row * 2048] = f2bf(acc[mf][nf][r]);
            }
        }
}

// ---------------- GEMM: C[M][N] = A[M][K] * Bt[N][K]^T  (bf16 in, fp32 acc) ----------------
template<int FP32OUT>
__global__ __launch_bounds__(256, 2) void gemm_bt_k(
    const u16* __restrict__ A, const u16* __restrict__ Bt, void* __restrict__ Cv,
    int M, int N, int K)
{
    __shared__ u16 As[128 * 64];
    __shared__ u16 Bs[128 * 64];
    const int tid = threadIdx.x, wave = tid >> 6, lane = tid & 63;
    const int quad = lane >> 4, l16 = lane & 15;
    const int m0 = blockIdx.y * 128, n0 = blockIdx.x * 128;
    const int mw = (wave & 1) * 64, nw = (wave >> 1) * 64;

    f32x4 zero = {0.f, 0.f, 0.f, 0.f};
    f32x4 acc[4][4];
    #pragma unroll
    for (int i = 0; i < 4; i++)
        #pragma unroll
        for (int j = 0; j < 4; j++) acc[i][j] = zero;

    const int sr = tid >> 3;          // 0..31
    const int sj = tid & 7;           // k-chunk
    const u16* ga0 = A  + (size_t)(m0 + sr) * K + sj * 8;
    const u16* gb0 = Bt + (size_t)(n0 + sr) * K + sj * 8;
    int woff[4];
    #pragma unroll
    for (int it = 0; it < 4; ++it) {
        int r = it * 32 + sr;
        woff[it] = r * 64 + ((sj ^ (r & 7)) * 8);
    }

    short8 abuf[4], bbuf[4];
    #pragma unroll
    for (int it = 0; it < 4; ++it) {
        abuf[it] = *(const short8*)(ga0 + (size_t)(it * 32) * K);
        bbuf[it] = *(const short8*)(gb0 + (size_t)(it * 32) * K);
    }
    #pragma unroll
    for (int it = 0; it < 4; ++it) {
        *(short8*)&As[woff[it]] = abuf[it];
        *(short8*)&Bs[woff[it]] = bbuf[it];
    }
    __syncthreads();

    const int rsw = l16 & 7;

    for (int kk = 0; kk < K; kk += 64) {
        const bool pre = (kk + 64 < K);
        if (pre) {
            #pragma unroll
            for (int it = 0; it < 4; ++it) {
                abuf[it] = *(const short8*)(ga0 + (size_t)(it * 32) * K + (kk + 64));
                bbuf[it] = *(const short8*)(gb0 + (size_t)(it * 32) * K + (kk + 64));
            }
        }
        #pragma unroll
        for (int ks = 0; ks < 2; ks++) {
            const int ch = ((ks * 4 + quad) ^ rsw) * 8;
            short8 af[4], bfr[4];
            #pragma unroll
            for (int mf = 0; mf < 4; mf++)
                af[mf] = *(const short8*)&As[(mw + mf * 16 + l16) * 64 + ch];
            #pragma unroll
            for (int nf = 0; nf < 4; nf++)
                bfr[nf] = *(const short8*)&Bs[(nw + nf * 16 + l16) * 64 + ch];
            #pragma unroll
            for (int mf = 0; mf < 4; mf++)
                #pragma unroll
                for (int nf = 0; nf < 4; nf++)
                    acc[mf][nf] = __builtin_amdgcn_mfma_f32_16x16x32_bf16(af[mf], bfr[nf], acc[mf][nf], 0, 0, 0);
        }
        if (pre) {
            __syncthreads();
            #pragma unroll
            for (int it = 0; it < 4; ++it) {
                *(short8*)&As[woff[it]] = abuf[it];
                *(short8*)&Bs[woff[it]] = bbuf[it];
            }
            __syncthreads();
        }
    }

    #pragma unroll
    for (int mf = 0; mf < 4; mf++)
        #pragma unroll
        for (int nf = 0; nf < 4; nf++)
            #pragma unroll
            for (int r = 0; r < 4; r++) {
                int row = m0 + mw + mf * 16 + quad * 4 + r;
                int col = n0 + nw + nf * 16 + l16;
                if (FP32OUT) ((float*)Cv)[(size_t)row * N + col] = acc[mf][nf][r];
                else         ((u16*) Cv)[(size_t)row * N + col] = f2bf(acc[mf][nf][r]);
            }
}

// =================================================================================
// Flash attention v2: 32x32 MFMA, swapped QK^T (keys in registers), in-register
// softmax + permlane32_swap P-fragment build (zero P-related LDS traffic).
// 256 threads = 4 waves x 32 q-rows = 128 q-rows/block; KVBLK=64.
// K/V staged via global_load_lds dbuf, counted vmcnt(8), chunk-XOR swizzle
// (c ^= row&7; linear DMA dest + inverse-swizzled per-lane source, rule 21).
// Max-free softmax (q pre-scaled 1/128 -> |s| <= ~1.6, exp never overflows).
// Fully-masked tiles are wave-uniformly skipped -> MFMA count exactly causal.
// =================================================================================
__device__ __forceinline__ void stage_kv32(u16* dst, const u16* kgp, const u16* vgp,
                                           int kt, int wave, int lane) {
    #pragma unroll
    for (int i = 0; i < 4; ++i) {
        const int g = i * 4 + wave;
        // K: Ks rows 4g..4g+3 (128 u16/row, 16 chunks); lane slot row=4g+(lane>>4), c'=lane&15
        const int krow = g * 4 + (lane >> 4);
        const int kc = (lane & 15) ^ (krow & 7);
        gload16(kgp + (size_t)(kt * 64 + krow) * 2048 + kc * 8, dst + g * 512);
        // V^T: Vs rows 8g..8g+7 (64 u16/row, 8 chunks); row=8g+(lane>>3), c'=lane&7
        const int vrow = g * 8 + (lane >> 3);
        const int vc = (lane & 7) ^ (vrow & 7);
        gload16(vgp + (size_t)vrow * AT_T + kt * 64 + vc * 8, dst + 8192 + g * 512);
    }
}

__global__ __launch_bounds__(256, 2) void attn32_k(
    const u16* __restrict__ q, const u16* __restrict__ k,
    const u16* __restrict__ vt, u16* __restrict__ o)
{
    __shared__ __align__(1024) u16 smem[2 * 16384];   // dbuf x (Ks 16KB + Vs 16KB)
    const int tid = threadIdx.x, wave = tid >> 6, lane = tid & 63;
    const int l32 = lane & 31, hi = lane >> 5;
    const int h = blockIdx.y, b = blockIdx.z;
    const int qb = (b & 1) ? (15 - (int)blockIdx.x) : (int)blockIdx.x;
    const int nkt = 2 * qb + 2;

    const u16* kgp = k  + ((size_t)(b * AT_T) * AT_H + h) * 128;
    const u16* vgp = vt + ((size_t)(b * AT_H + h) * 128) * (size_t)AT_T;

    // Q in regs: qf[kc] = Q[qrow][d = kc*16 + hi*8 + (0..8)]  (B-frag for 32x32x16)
    short8 qf[8];
    {
        const u16* qp = q + ((size_t)(b * AT_T + qb * 128 + wave * 32 + l32) * AT_H + h) * 128 + hi * 8;
        #pragma unroll
        for (int kc = 0; kc < 8; ++kc)
            qf[kc] = *(const short8*)(qp + kc * 16);
    }

    const f32x16 z16 = {0.f,0.f,0.f,0.f,0.f,0.f,0.f,0.f,0.f,0.f,0.f,0.f,0.f,0.f,0.f,0.f};
    f32x16 Oacc[4];
    #pragma unroll
    for (int i = 0; i < 4; ++i) Oacc[i] = z16;
    float l_i = 0.f;

    // prologue: stage tiles 0 and 1, wait tile 0 (vmcnt(8) leaves tile1's 8 in flight)
    stage_kv32(smem,          kgp, vgp, 0, wave, lane);
    stage_kv32(smem + 16384,  kgp, vgp, 1, wave, lane);
    asm volatile("s_waitcnt vmcnt(8)" ::: "memory");
    __builtin_amdgcn_s_barrier();
    asm volatile("" ::: "memory");

    for (int kt = 0; kt < nkt; ++kt) {
        u16* buf = smem + (kt & 1) * 16384;
        const u16* Ks = buf;
        const u16* Vs = buf + 8192;
        const int lkey0 = kt * 64 - qb * 128;      // block-local key base (may be <0)
        const bool act = (lkey0 <= wave * 32 + 31); // wave-uniform skip of fully-masked tiles

        if (act) {
            // ---- QK^T: acc[kch][reg] = S[key][qrow=l32]; keys = (r&3)+8*(r>>2)+4*hi+32*kch
            f32x16 acc[2];
            acc[0] = z16; acc[1] = z16;
            #pragma unroll
            for (int kch = 0; kch < 2; ++kch) {
                #pragma unroll
                for (int kc = 0; kc < 8; ++kc) {
                    const int row = kch * 32 + l32;
                    const int cc = (kc * 2 + hi) ^ (lane & 7);
                    short8 af = *(const short8*)&Ks[row * 128 + cc * 8];
                    acc[kch] = __builtin_amdgcn_mfma_f32_32x32x16_bf16(af, qf[kc], acc[kch], 0, 0, 0);
                }
            }
            // ---- masked exp (max-free) + row-sum; mask compare is exact for all tiles
            float rs = 0.f;
            #pragma unroll
            for (int kch = 0; kch < 2; ++kch)
                #pragma unroll
                for (int r = 0; r < 16; ++r) {
                    const int keyb = lkey0 + kch * 32 + (r & 3) + 8 * (r >> 2) + 4 * hi;
                    float sv = acc[kch][r];
                    sv = (keyb > wave * 32 + l32) ? -1e30f : sv;
                    const float e = __expf(sv);
                    acc[kch][r] = e;
                    rs += e;
                }
            rs += __shfl_xor(rs, 32, 64);   // lanes l and l+32 hold the same qrow
            l_i += rs;
            // ---- PV: per 16-key window, build P A-frag via cvt_pk + 2 permlane32_swap
            #pragma unroll
            for (int w16 = 0; w16 < 4; ++w16) {
                const int ch = w16 >> 1, rb = (w16 & 1) * 8;
                unsigned A0 = pack_bf2(acc[ch][rb + 0], acc[ch][rb + 1]);
                unsigned A1 = pack_bf2(acc[ch][rb + 2], acc[ch][rb + 3]);
                unsigned B0 = pack_bf2(acc[ch][rb + 4], acc[ch][rb + 5]);
                unsigned B1 = pack_bf2(acc[ch][rb + 6], acc[ch][rb + 7]);
                // swap: A0' = {A0.lo32lanes, B0 from partner}, B0' = {A0 from partner, B0}
                asm volatile("v_permlane32_swap_b32 %0, %1" : "+v"(A0), "+v"(B0));
                asm volatile("v_permlane32_swap_b32 %0, %1" : "+v"(A1), "+v"(B1));
                union { u32x4 w; short8 s; } pa;
                pa.w.x = A0; pa.w.y = A1; pa.w.z = B0; pa.w.w = B1;  // k-pairs (0,1)(2,3)(4,5)(6,7)+hi*8
                #pragma unroll
                for (int dblk = 0; dblk < 4; ++dblk) {
                    const int rowv = dblk * 32 + l32;
                    const int cv = (w16 * 2 + hi) ^ (lane & 7);
                    short8 vf = *(const short8*)&Vs[rowv * 64 + cv * 8];
                    Oacc[dblk] = __builtin_amdgcn_mfma_f32_32x32x16_bf16(pa.s, vf, Oacc[dblk], 0, 0, 0);
                }
            }
        }

        // ---- barrier pair with liveness-correct staging (R3 pattern, vmcnt(8))
        asm volatile("s_waitcnt lgkmcnt(0)" ::: "memory");
        __builtin_amdgcn_s_barrier();
        asm volatile("" ::: "memory");
        if (kt + 2 < nkt) {
            stage_kv32(buf, kgp, vgp, kt + 2, wave, lane);   // into the buffer just freed
            asm volatile("s_waitcnt vmcnt(8)" ::: "memory"); // tile kt+1 fully landed
        } else if (kt + 1 < nkt) {
            asm volatile("s_waitcnt vmcnt(0)" ::: "memory");
        }
        __builtin_amdgcn_s_barrier();
        asm volatile("" ::: "memory");
    }

    // ---- epilogue: distribute l_i (held at lane = qrow) to the C-layout rows, store
    float linv[16];
    #pragma unroll
    for (int r = 0; r < 16; ++r) {
        const int qr = (r & 3) + 8 * (r >> 2) + 4 * hi;
        linv[r] = 1.0f / __shfl(l_i, qr, 64);
    }
    u16* op = o + ((size_t)(b * AT_T + qb * 128 + wave * 32) * AT_H + h) * 128;
    #pragma unroll
    for (int dblk = 0; dblk < 4; ++dblk)
        #pragma unroll
        for (int r = 0; r < 16; ++r) {
            const int qr = (r & 3) + 8 * (r >> 2) + 4 * hi;
            op[(size_t)qr * 2048 + dblk * 32 + l32] = f2bf(Oacc[dblk][r] * linv[r]);
        }
}

// ---------------- launch ----------------
extern "C" void kernel_launch(void* const* d_in, const int* in_sizes, int n_in,
                              void* d_out, int out_size, void* d_ws, size_t ws_size,
                              hipStream_t stream) {
    const float* x    = (const float*)d_in[0];
    const float* w_aq = (const float*)d_in[1];
    const float* w_ak = (const float*)d_in[2];
    const float* w_av = (const float*)d_in[3];
    const float* w_ao = (const float*)d_in[4];
    float* outp = (float*)d_out;

    u16* ws   = (u16*)d_ws;
    u16* xb   = ws;                           // [4096][2048]      x, bf16
    u16* wqb  = xb   + (size_t)NROW * HD;     // [6144 n][2048 k]  (wq|wk|wv transposed)
    u16* waob = wqb  + (size_t)3 * HD * AT_M; // [2048 m][2048 hd] (w_ao^T)
    u16* qb   = waob + (size_t)HD * AT_M;     // [B,T,H,D] (then kb, vb contiguous)
    u16* kb   = qb   + (size_t)NROW * HD;
    u16* vb   = kb   + (size_t)NROW * HD;
    u16* vtb  = vb   + (size_t)NROW * HD;     // [B,H,D,T]
    u16* ob   = xb;                           // alias: xb dead after projections

    // 1) casts / transposes
    cast_bf16_k<<<(NROW * HD / 4 + 255) / 256, 256, 0, stream>>>(x, xb, NROW * HD / 4);
    dim3 tb(32, 8);
    tcast3_k<<<dim3(AT_D / 32, AT_M / 32, 48), tb, 0, stream>>>(w_aq, w_ak, w_av, wqb);
    tcast_k<<<dim3(AT_M / 32, HD / 32), tb, 0, stream>>>(w_ao, waob, HD, AT_M);

    // 2) fused QKV projection: 256x192 tile, grid 32x16 = 512 blocks
    gemm256_qkv_k<<<dim3(3 * HD / 192, NROW / 256), 512, 0, stream>>>(xb, wqb, qb, NROW, 3 * HD, AT_M);

    // 3) RoPE on q,k (q scaled by 1/128)
    rope_k<<<(NROW * AT_H * 64 + 255) / 256, 256, 0, stream>>>(qb, kb, NROW * AT_H * 64);

    // 4) v -> [B,H,D,T]
    tbf16_k<<<dim3(HD / 32, AT_T / 32, AT_B), tb, 0, stream>>>(vb, vtb, AT_T, HD);

    // 5) attention v2: 32x32 swapped-QK, in-register softmax, permlane P-frags
    attn32_k<<<dim3(16, AT_H, AT_B), 256, 0, stream>>>(qb, kb, vtb, ob);

    // 6) output projection (fp32 out)
    gemm_bt_k<1><<<dim3(AT_M / 128, NROW / 128), 256, 0, stream>>>(ob, waob, outp, NROW, AT_M, HD);
}